// Round 12
// baseline (176.682 us; speedup 1.0000x reference)
//
#include <hip/hip_runtime.h>
#include <hip/hip_bf16.h>
#include <cmath>

#define N_NODES 8192
#define F_INPUT 59
#define H 128
#define K 32
#define NECK 512
#define GPER 8
#define NG 1024
#define EPS_BN 1e-5f
#define DPITCH 136   // bf16 row pitch (272 B, 16B-aligned)
#define XPITCH 72    // proj x-plane pitch (144 B, 16B-aligned)

typedef short bf16x8 __attribute__((ext_vector_type(8)));
typedef float f32x16 __attribute__((ext_vector_type(16)));

// truncation hi/lo split
__device__ __forceinline__ void split_bf(float v, short& hi, short& lo) {
    unsigned u = __float_as_uint(v);
    float hif = __uint_as_float(u & 0xffff0000u);
    hi = (short)(u >> 16);
    lo = (short)(__float_as_uint(v - hif) >> 16);
}

// B-frag flat index for 32x32x16: c = ct*32+ln, k = s*16+hf*8+kk
__device__ __forceinline__ int bfrag_idx(int k, int c, int k16) {
    int ct = c >> 5, ln = c & 31;
    int s = k >> 4, hf = (k >> 3) & 1, kk = k & 7;
    return ((((ct * k16 + s) * 2 + hf) * 32 + ln) * 8 + kk);
}

// ---------------------------------------------------------------------------
// Prep (fused) -- R15: unroll-4 on the serial k loop (59 gating blocks,
// latency-bound on dependent loads).
// ---------------------------------------------------------------------------
__global__ __launch_bounds__(256) void prep_kernel(
    const float* __restrict__ lin_w,
    const float* __restrict__ src_w, const float* __restrict__ dst_w,
    const float* __restrict__ posnn_w,
    const float* __restrict__ attnn_w, const float* __restrict__ neck_w,
    short* __restrict__ w3hi, short* __restrict__ w3lo,
    short* __restrict__ pwhi, short* __restrict__ pwlo,
    short* __restrict__ awhi, short* __restrict__ awlo,
    short* __restrict__ nwhi, short* __restrict__ nwlo)
{
    __shared__ float s1[128], s2[128];
    const int b = blockIdx.x;
    if (b < F_INPUT) {
        const int c = threadIdx.x & 127;
        const int half = threadIdx.x >> 7;
        float a1 = 0.f, a2 = 0.f;
        const int kb = half * 64;
        #pragma unroll 4
        for (int k = kb; k < kb + 64; k++) {
            float wa = attnn_w[k * H + c];
            a1 = fmaf(src_w[b * H + k], wa, a1);
            a2 = fmaf(dst_w[b * H + k], wa, a2);
        }
        if (half == 1) { s1[c] = a1; s2[c] = a2; }
        __syncthreads();
        if (half == 0) {
            a1 += s1[c]; a2 += s2[c];
            short hi, lo; int idx;
            split_bf(lin_w[b * H + c], hi, lo);
            idx = bfrag_idx(b, c, 4);       w3hi[idx] = hi; w3lo[idx] = lo;
            split_bf(a1, hi, lo);
            idx = bfrag_idx(b, 128 + c, 4); w3hi[idx] = hi; w3lo[idx] = lo;
            split_bf(a2, hi, lo);
            idx = bfrag_idx(b, 256 + c, 4); w3hi[idx] = hi; w3lo[idx] = lo;
        }
    } else if (b == F_INPUT) {
        for (int t = threadIdx.x; t < 5 * 384; t += 256) {
            int k = F_INPUT + t / 384, c = t % 384;
            int idx = bfrag_idx(k, c, 4);
            w3hi[idx] = 0; w3lo[idx] = 0;
        }
    } else if (b == F_INPUT + 1) {
        // posnn pack: 2048 entries, K16=1
        for (int idx = threadIdx.x; idx < 2048; idx += 256) {
            int kk = idx & 7; int t = idx >> 3;
            int l2 = t & 31; t >>= 5;
            int hb = t & 1;  t >>= 1;
            int ct = t;                       // 0..3
            int k = hb * 8 + kk, c = ct * 32 + l2;
            float wv = (k < 6) ? posnn_w[k * H + c] : 0.f;
            short hi, lo; split_bf(wv, hi, lo);
            pwhi[idx] = hi; pwlo[idx] = lo;
        }
    } else if (b < F_INPUT + 2 + 64) {
        int idx = (b - F_INPUT - 2) * 256 + threadIdx.x;
        int kk = idx & 7; int t = idx >> 3;
        int l2 = t & 31; t >>= 5;
        int hb = t & 1;  t >>= 1;
        int s  = t & 7;  t >>= 3;
        int c = t * 32 + l2, k = s * 16 + hb * 8 + kk;
        short hi, lo; split_bf(attnn_w[k * H + c], hi, lo);
        awhi[idx] = hi; awlo[idx] = lo;
    } else {
        int idx = (b - F_INPUT - 2 - 64) * 256 + threadIdx.x;
        int kk = idx & 7; int t = idx >> 3;
        int l2 = t & 31; t >>= 5;
        int hb = t & 1;  t >>= 1;
        int s  = t & 7;  t >>= 3;
        int c = t * 32 + l2, k = s * 16 + hb * 8 + kk;
        short hi, lo; split_bf(neck_w[k * NECK + c], hi, lo);
        nwhi[idx] = hi; nwlo[idx] = lo;
    }
}

// ---------------------------------------------------------------------------
// Kernel A: proj via MFMA. R14 structure (768 threads, 12 waves = 12 ct
// tiles, 1 ct/wave) + R15 setprio around the MFMA cluster.
// ---------------------------------------------------------------------------
__global__ __launch_bounds__(768) void proj_kernel(
    const float* __restrict__ x, const float* __restrict__ lin_b,
    const short* __restrict__ w3hi, const short* __restrict__ w3lo,
    float2* __restrict__ vx, float* __restrict__ xdW)
{
    const int n0 = blockIdx.x * 32;
    const int tid = threadIdx.x;
    const int ct = tid >> 6;              // wave = ct tile, 0..11
    const int lane = tid & 63;
    const int hf = lane >> 5;
    const int ln = lane & 31;

    __shared__ __align__(16) short xhi[32][XPITCH];
    __shared__ __align__(16) short xlo[32][XPITCH];

    for (int idx = tid; idx < 32 * F_INPUT; idx += 768) {
        int n = idx / F_INPUT, k = idx - n * F_INPUT;
        short hi, lo; split_bf(x[n0 * F_INPUT + idx], hi, lo);
        xhi[n][k] = hi; xlo[n][k] = lo;
    }
    if (tid < 32 * 5) {
        int n = tid / 5, k = F_INPUT + tid % 5;
        xhi[n][k] = 0; xlo[n][k] = 0;
    }
    __syncthreads();

    f32x16 acc;
    #pragma unroll
    for (int r = 0; r < 16; r++) acc[r] = 0.f;

    __builtin_amdgcn_s_setprio(1);
    #pragma unroll
    for (int s = 0; s < 4; s++) {
        bf16x8 ah = *(const bf16x8*)&xhi[ln][s * 16 + hf * 8];
        bf16x8 al = *(const bf16x8*)&xlo[ln][s * 16 + hf * 8];
        const int boff = (((ct * 4 + s) * 2 + hf) * 32 + ln) * 8;
        bf16x8 bh = *(const bf16x8*)&w3hi[boff];
        bf16x8 bl = *(const bf16x8*)&w3lo[boff];
        acc = __builtin_amdgcn_mfma_f32_32x32x16_bf16(ah, bl, acc, 0, 0, 0);
        acc = __builtin_amdgcn_mfma_f32_32x32x16_bf16(al, bh, acc, 0, 0, 0);
        acc = __builtin_amdgcn_mfma_f32_32x32x16_bf16(ah, bh, acc, 0, 0, 0);
    }
    __builtin_amdgcn_s_setprio(0);

    const int tpl = ct >> 2;              // output plane 0..2
    const int c = (ct & 3) * 32 + ln;
    if (tpl == 0) {
        const float lb = lin_b[c];
        #pragma unroll
        for (int r = 0; r < 16; r++) {
            int node = n0 + (r & 3) + 8 * (r >> 2) + 4 * hf;
            ((float*)&vx[node * H + c])[1] = acc[r] + lb;   // vx.y = v
        }
    } else if (tpl == 1) {
        #pragma unroll
        for (int r = 0; r < 16; r++) {
            int node = n0 + (r & 3) + 8 * (r >> 2) + 4 * hf;
            ((float*)&vx[node * H + c])[0] = acc[r];        // vx.x = a_src
        }
    } else {
        #pragma unroll
        for (int r = 0; r < 16; r++) {
            int node = n0 + (r & 3) + 8 * (r >> 2) + 4 * hf;
            xdW[node * H + c] = acc[r];
        }
    }
}

// ---------------------------------------------------------------------------
// Kernel B: edge stage -- R11 structure; R15: __launch_bounds__(256,6).
// Unified-reg cap 85 vs ~76 peak live (VGPR 44 + 32 AGPR acc) -> no spill,
// 6 blocks/CU (LDS 22KB allows 7). Revert trigger: WRITE_SIZE > 10 MB.
// ---------------------------------------------------------------------------
__global__ __launch_bounds__(256, 6) void edge_kernel(
    const float* __restrict__ pos, const float* __restrict__ normal,
    const int* __restrict__ src,
    const float2* __restrict__ vx, const float* __restrict__ xdW,
    const float* __restrict__ posnn_b, const float* __restrict__ posnn_g,
    const float* __restrict__ posnn_bb,
    const float* __restrict__ attnn_b,
    const float* __restrict__ attnn_g, const float* __restrict__ attnn_bb,
    const short* __restrict__ pwhi, const short* __restrict__ pwlo,
    const short* __restrict__ awhi, const short* __restrict__ awlo,
    unsigned* __restrict__ h2)
{
    // bijective chunked swizzle: 4096 blocks, 8 XCDs, 512 blocks/chunk
    const int bid = blockIdx.x;
    const int swz = (bid & 7) * 512 + (bid >> 3);
    const int i0 = swz * 2;
    const int tid = threadIdx.x;
    const int wave = tid >> 6;
    const int lane = tid & 63;
    const int hf = lane >> 5;
    const int ln = lane & 31;

    __shared__ int srcs[2][K];
    __shared__ __align__(16) short relh[64][16];
    __shared__ __align__(16) short rell[64][16];
    __shared__ __align__(16) short dhi[64][DPITCH];

    if (tid < 64) {
        int n = tid >> 5, jj = tid & 31;
        int i = i0 + n;
        int s = src[i * K + jj];
        srcs[n][jj] = s;
        short h_, l_;
        #pragma unroll
        for (int k = 0; k < 3; k++) {
            split_bf(pos[i * 3 + k] - pos[s * 3 + k], h_, l_);
            relh[tid][k] = h_; rell[tid][k] = l_;
            split_bf(normal[i * 3 + k] - normal[s * 3 + k], h_, l_);
            relh[tid][k + 3] = h_; rell[tid][k + 3] = l_;
        }
        #pragma unroll
        for (int k = 6; k < 16; k++) { relh[tid][k] = 0; rell[tid][k] = 0; }
    }

    // per-channel constants (c = cc for this lane)
    const int cc = wave * 32 + ln;
    const float ps  = posnn_g[cc] * rsqrtf(1.f + EPS_BN);
    const float pbn = fmaf(posnn_b[cc], ps, posnn_bb[cc]);
    const float as_ = attnn_g[cc] * rsqrtf(1.f + EPS_BN);
    const float abb = attnn_bb[cc];
    const float ab  = attnn_b[cc];

    // posnn B-frag (K16=1, ct=wave)
    const bf16x8 pbh = *(const bf16x8*)&pwhi[((wave * 2 + hf) * 32 + ln) * 8];
    const bf16x8 pbl = *(const bf16x8*)&pwlo[((wave * 2 + hf) * 32 + ln) * 8];

    // hoist the per-node alpha bases (hides L2 latency under delta phase)
    const float base0 = xdW[(i0 + 0) * H + cc] + ab;
    const float base1 = xdW[(i0 + 1) * H + cc] + ab;

    __syncthreads();

    // ---- delta via MFMA for both nodes; bf16-hi delta stored to LDS
    #pragma unroll
    for (int n = 0; n < 2; n++) {
        bf16x8 ah = *(const bf16x8*)&relh[32 * n + ln][hf * 8];
        bf16x8 al = *(const bf16x8*)&rell[32 * n + ln][hf * 8];
        f32x16 da;
        #pragma unroll
        for (int r = 0; r < 16; r++) da[r] = 0.f;
        da = __builtin_amdgcn_mfma_f32_32x32x16_bf16(ah, pbl, da, 0, 0, 0);
        da = __builtin_amdgcn_mfma_f32_32x32x16_bf16(al, pbh, da, 0, 0, 0);
        da = __builtin_amdgcn_mfma_f32_32x32x16_bf16(ah, pbh, da, 0, 0, 0);
        #pragma unroll
        for (int r = 0; r < 16; r++) {
            int j = (r & 3) + 8 * (r >> 2) + 4 * hf;
            float d = fmaxf(fmaf(da[r], ps, pbn), 0.f);
            dhi[32 * n + j][cc] = (short)(__float_as_uint(d) >> 16);
        }
    }
    __syncthreads();

    // ---- attnn MFMA: s-loop outer, both nodes accumulate per B-frag load.
    //      A = delta (bf16-hi only); B = attnn_w hi+lo. C init = alpha base.
    const short* whb = awhi + wave * 8 * 2 * 32 * 8;
    const short* wlb = awlo + wave * 8 * 2 * 32 * 8;

    f32x16 acc[2];
    #pragma unroll
    for (int r = 0; r < 16; r++) { acc[0][r] = base0; acc[1][r] = base1; }

    __builtin_amdgcn_s_setprio(1);
    #pragma unroll
    for (int s = 0; s < 8; s++) {
        const int boff = ((s * 2 + hf) * 32 + ln) * 8;
        bf16x8 bh = *(const bf16x8*)&whb[boff];
        bf16x8 bl = *(const bf16x8*)&wlb[boff];
        #pragma unroll
        for (int n = 0; n < 2; n++) {
            bf16x8 ah = *(const bf16x8*)&dhi[32 * n + ln][s * 16 + hf * 8];
            acc[n] = __builtin_amdgcn_mfma_f32_32x32x16_bf16(ah, bl, acc[n], 0, 0, 0);
            acc[n] = __builtin_amdgcn_mfma_f32_32x32x16_bf16(ah, bh, acc[n], 0, 0, 0);
        }
    }
    __builtin_amdgcn_s_setprio(0);

    // ---- softmax epilogue per node (gathers issued here; 16 in flight)
    #pragma unroll
    for (int n = 0; n < 2; n++) {
        const int i = i0 + n;
        float2 gvn[16];
        #pragma unroll
        for (int r = 0; r < 16; r++) {
            int j = (r & 3) + 8 * (r >> 2) + 4 * hf;
            gvn[r] = vx[srcs[n][j] * H + cc];
        }
        float a[16], vv[16];
        #pragma unroll
        for (int r = 0; r < 16; r++) {
            int j = (r & 3) + 8 * (r >> 2) + 4 * hf;
            unsigned dh = (unsigned short)dhi[32 * n + j][cc];
            float av = fmaxf(fmaf(acc[n][r] - gvn[r].x, as_, abb), 0.f);
            a[r] = av;
            vv[r] = gvn[r].y + __uint_as_float(dh << 16);
        }
        // depth-4 max tree (all a[] >= 0 from relu)
        float m01 = fmaxf(a[0], a[1]),  m23 = fmaxf(a[2], a[3]);
        float m45 = fmaxf(a[4], a[5]),  m67 = fmaxf(a[6], a[7]);
        float m89 = fmaxf(a[8], a[9]),  mab = fmaxf(a[10], a[11]);
        float mcd = fmaxf(a[12], a[13]), mef = fmaxf(a[14], a[15]);
        float m0123 = fmaxf(m01, m23), m4567 = fmaxf(m45, m67);
        float m89ab = fmaxf(m89, mab), mcdef = fmaxf(mcd, mef);
        float m = fmaxf(fmaxf(m0123, m4567), fmaxf(m89ab, mcdef));
        m = fmaxf(m, __shfl_xor(m, 32, 64));

        float dac0 = 0.f, dac1 = 0.f, dac2 = 0.f, dac3 = 0.f;
        float hac0 = 0.f, hac1 = 0.f, hac2 = 0.f, hac3 = 0.f;
        #pragma unroll
        for (int r = 0; r < 16; r += 4) {
            float e0 = __expf(a[r + 0] - m);
            float e1 = __expf(a[r + 1] - m);
            float e2 = __expf(a[r + 2] - m);
            float e3 = __expf(a[r + 3] - m);
            dac0 += e0; dac1 += e1; dac2 += e2; dac3 += e3;
            hac0 = fmaf(e0, vv[r + 0], hac0);
            hac1 = fmaf(e1, vv[r + 1], hac1);
            hac2 = fmaf(e2, vv[r + 2], hac2);
            hac3 = fmaf(e3, vv[r + 3], hac3);
        }
        float den = (dac0 + dac1) + (dac2 + dac3);
        float hsum = (hac0 + hac1) + (hac2 + hac3);
        den += __shfl_xor(den, 32, 64);
        hsum += __shfl_xor(hsum, 32, 64);
        hsum *= 1.f / (den + 1e-16f);
        if (hf == 0) {
            unsigned u = __float_as_uint(hsum);
            unsigned hib = u & 0xffff0000u;
            unsigned lo = __float_as_uint(hsum - __uint_as_float(hib)) >> 16;
            h2[i * H + cc] = (lo << 16) | (u >> 16);
        }
    }
}

// ---------------------------------------------------------------------------
// Kernel C (fused): neck MFMA + bn_relu + residue max-pool + head.
// R14 structure (1024 threads, 16 waves, 1 ct/wave, mlp1 16-way k-split)
// + R15 setprio around the MFMA cluster.
// ---------------------------------------------------------------------------
__global__ __launch_bounds__(1024) void neck_head_kernel(
    const unsigned* __restrict__ h2,
    const short* __restrict__ nwhi, const short* __restrict__ nwlo,
    const float* __restrict__ neck_b, const float* __restrict__ neck_g,
    const float* __restrict__ neck_bb,
    const float* __restrict__ mask_t,
    const float* __restrict__ mlp1_w, const float* __restrict__ mlp1_b,
    const float* __restrict__ mlp1_g, const float* __restrict__ mlp1_bb,
    const float* __restrict__ mlp2_w, const float* __restrict__ mlp2_b,
    float* __restrict__ out)
{
    const int blk = blockIdx.x;
    const int n0 = blk * 32;
    const int tid = threadIdx.x;
    const int wave = tid >> 6;            // 0..15
    const int lane = tid & 63;
    const int hf = lane >> 5;
    const int ln = lane & 31;

    __shared__ __align__(16) short a_hi[32][DPITCH];
    __shared__ __align__(16) short a_lo[32][DPITCH];
    __shared__ float gfeat_l[4][NECK];
    __shared__ float red_l[16][4][256];

    for (int d = tid; d < 32 * H; d += 1024) {
        unsigned u = h2[(n0 + (d >> 7)) * H + (d & 127)];
        a_hi[d >> 7][d & 127] = (short)(u & 0xffffu);
        a_lo[d >> 7][d & 127] = (short)(u >> 16);
    }
    __syncthreads();

    f32x16 acc;
    #pragma unroll
    for (int r = 0; r < 16; r++) acc[r] = 0.f;

    const int ct = wave;                  // 1 ct tile per wave
    __builtin_amdgcn_s_setprio(1);
    #pragma unroll
    for (int s = 0; s < 8; s++) {
        bf16x8 ah = *(const bf16x8*)&a_hi[ln][s * 16 + hf * 8];
        bf16x8 al = *(const bf16x8*)&a_lo[ln][s * 16 + hf * 8];
        const int boff = (((ct * 8 + s) * 2 + hf) * 32 + ln) * 8;
        bf16x8 bh = *(const bf16x8*)&nwhi[boff];
        bf16x8 bl = *(const bf16x8*)&nwlo[boff];
        acc = __builtin_amdgcn_mfma_f32_32x32x16_bf16(ah, bl, acc, 0, 0, 0);
        acc = __builtin_amdgcn_mfma_f32_32x32x16_bf16(al, bh, acc, 0, 0, 0);
        acc = __builtin_amdgcn_mfma_f32_32x32x16_bf16(ah, bh, acc, 0, 0, 0);
    }
    __builtin_amdgcn_s_setprio(0);

    {
        const int c = ct * 32 + ln;
        const float s  = neck_g[c] * rsqrtf(1.f + EPS_BN);
        const float bnb = fmaf(neck_b[c], s, neck_bb[c]);
        #pragma unroll
        for (int g = 0; g < 4; g++) {
            float m = 0.f;
            #pragma unroll
            for (int q = 0; q < 4; q++)
                m = fmaxf(m, fmaf(acc[4 * g + q], s, bnb));
            m = fmaxf(m, __shfl_xor(m, 32, 64));
            if (hf == 0) gfeat_l[g][c] = m;
        }
    }
    __syncthreads();

    const int c4 = lane;
    float ph[4][4];
    #pragma unroll
    for (int g = 0; g < 4; g++)
        #pragma unroll
        for (int mm = 0; mm < 4; mm++) ph[g][mm] = 0.f;

    const int k0 = wave * 32;             // 32 k per wave
    for (int k = 0; k < 32; k += 4) {
        float4 gv[4];
        #pragma unroll
        for (int g = 0; g < 4; g++) gv[g] = *(const float4*)&gfeat_l[g][k0 + k];
        #pragma unroll
        for (int kk = 0; kk < 4; kk++) {
            float w0 = mlp1_w[(k0 + k + kk) * 256 + c4];
            float w1 = mlp1_w[(k0 + k + kk) * 256 + c4 + 64];
            float w2 = mlp1_w[(k0 + k + kk) * 256 + c4 + 128];
            float w3 = mlp1_w[(k0 + k + kk) * 256 + c4 + 192];
            #pragma unroll
            for (int g = 0; g < 4; g++) {
                float gvk = (&gv[g].x)[kk];
                ph[g][0] = fmaf(gvk, w0, ph[g][0]);
                ph[g][1] = fmaf(gvk, w1, ph[g][1]);
                ph[g][2] = fmaf(gvk, w2, ph[g][2]);
                ph[g][3] = fmaf(gvk, w3, ph[g][3]);
            }
        }
    }
    #pragma unroll
    for (int g = 0; g < 4; g++)
        #pragma unroll
        for (int mm = 0; mm < 4; mm++)
            red_l[wave][g][c4 + 64 * mm] = ph[g][mm];
    __syncthreads();

    if (wave < 4) {
        const int g = wave;
        float part = 0.f;
        #pragma unroll
        for (int mm = 0; mm < 4; mm++) {
            const int c = c4 + 64 * mm;
            float sum = mlp1_b[c];
            #pragma unroll
            for (int w = 0; w < 16; w++) sum += red_l[w][g][c];
            float s = mlp1_g[c] * rsqrtf(1.f + EPS_BN);
            float val = fmaxf(fmaf(sum, s, mlp1_bb[c]), 0.f);
            part = fmaf(val, mlp2_w[c], part);
        }
        #pragma unroll
        for (int off = 32; off > 0; off >>= 1) part += __shfl_xor(part, off, 64);
        if (lane == 0) {
            const int gg = blk * 4 + g;
            float mm = mask_t[gg * GPER];
            #pragma unroll
            for (int n = 1; n < GPER; n++) mm = fmaxf(mm, mask_t[gg * GPER + n]);
            out[gg] = (mm == 1.0f) ? (part + mlp2_b[0]) : 0.f;
        }
    }
}

// ---------------------------------------------------------------------------
extern "C" void kernel_launch(void* const* d_in, const int* in_sizes, int n_in,
                              void* d_out, int out_size, void* d_ws, size_t ws_size,
                              hipStream_t stream)
{
    const float* x        = (const float*)d_in[0];
    const float* pos      = (const float*)d_in[1];
    const float* normal   = (const float*)d_in[2];
    const float* mask_t   = (const float*)d_in[3];
    const int*   src      = (const int*)d_in[5];
    const float* lin_w    = (const float*)d_in[7];
    const float* lin_b    = (const float*)d_in[8];
    const float* src_w    = (const float*)d_in[9];
    const float* dst_w    = (const float*)d_in[10];
    const float* posnn_w  = (const float*)d_in[11];
    const float* posnn_b  = (const float*)d_in[12];
    const float* posnn_g  = (const float*)d_in[13];
    const float* posnn_bb = (const float*)d_in[14];
    const float* attnn_w  = (const float*)d_in[15];
    const float* attnn_b  = (const float*)d_in[16];
    const float* attnn_g  = (const float*)d_in[17];
    const float* attnn_bb = (const float*)d_in[18];
    const float* neck_w   = (const float*)d_in[19];
    const float* neck_b   = (const float*)d_in[20];
    const float* neck_g   = (const float*)d_in[21];
    const float* neck_bb  = (const float*)d_in[22];
    const float* mlp1_w   = (const float*)d_in[23];
    const float* mlp1_b   = (const float*)d_in[24];
    const float* mlp1_g   = (const float*)d_in[25];
    const float* mlp1_bb  = (const float*)d_in[26];
    const float* mlp2_w   = (const float*)d_in[27];
    const float* mlp2_b   = (const float*)d_in[28];

    float* ws = (float*)d_ws;
    float2*   vx   = (float2*)ws;                              // N*H float2
    float*    xdW  = (float*)(vx + (size_t)N_NODES * H);       // N*H
    unsigned* h2   = (unsigned*)(xdW + (size_t)N_NODES * H);   // N*H
    short*    w3hi = (short*)(h2 + (size_t)N_NODES * H);       // 24576
    short*    w3lo = w3hi + 24576;
    short*    pwhi = w3lo + 24576;                             // 2048
    short*    pwlo = pwhi + 2048;
    short*    awhi = pwlo + 2048;                              // 16384
    short*    awlo = awhi + H * H;
    short*    nwhi = awlo + H * H;                             // 65536
    short*    nwlo = nwhi + H * NECK;

    prep_kernel<<<F_INPUT + 2 + 64 + 256, 256, 0, stream>>>(
        lin_w, src_w, dst_w, posnn_w, attnn_w, neck_w,
        w3hi, w3lo, pwhi, pwlo, awhi, awlo, nwhi, nwlo);
    proj_kernel<<<N_NODES / 32, 768, 0, stream>>>(x, lin_b, w3hi, w3lo, vx, xdW);
    edge_kernel<<<N_NODES / 2, 256, 0, stream>>>(pos, normal, src, vx, xdW,
                                                 posnn_b, posnn_g, posnn_bb,
                                                 attnn_b, attnn_g, attnn_bb,
                                                 pwhi, pwlo, awhi, awlo, h2);
    neck_head_kernel<<<N_NODES / 32, 1024, 0, stream>>>(
        h2, nwhi, nwlo, neck_b, neck_g, neck_bb, mask_t,
        mlp1_w, mlp1_b, mlp1_g, mlp1_bb, mlp2_w, mlp2_b, (float*)d_out);
}

// Round 13
// 173.349 us; speedup vs baseline: 1.0192x; 1.0192x over previous
//
#include <hip/hip_runtime.h>
#include <hip/hip_bf16.h>
#include <cmath>

#define N_NODES 8192
#define F_INPUT 59
#define H 128
#define K 32
#define NECK 512
#define GPER 8
#define NG 1024
#define EPS_BN 1e-5f
#define DPITCH 136   // bf16 row pitch (272 B, 16B-aligned)
#define XPITCH 72    // proj x-plane pitch (144 B, 16B-aligned)

typedef short bf16x8 __attribute__((ext_vector_type(8)));
typedef float f32x16 __attribute__((ext_vector_type(16)));

// truncation hi/lo split
__device__ __forceinline__ void split_bf(float v, short& hi, short& lo) {
    unsigned u = __float_as_uint(v);
    float hif = __uint_as_float(u & 0xffff0000u);
    hi = (short)(u >> 16);
    lo = (short)(__float_as_uint(v - hif) >> 16);
}

// B-frag flat index for 32x32x16: c = ct*32+ln, k = s*16+hf*8+kk
__device__ __forceinline__ int bfrag_idx(int k, int c, int k16) {
    int ct = c >> 5, ln = c & 31;
    int s = k >> 4, hf = (k >> 3) & 1, kk = k & 7;
    return ((((ct * k16 + s) * 2 + hf) * 32 + ln) * 8 + kk);
}

// ---------------------------------------------------------------------------
// Prep (fused) -- R15: unroll-4 on the serial k loop.
// ---------------------------------------------------------------------------
__global__ __launch_bounds__(256) void prep_kernel(
    const float* __restrict__ lin_w,
    const float* __restrict__ src_w, const float* __restrict__ dst_w,
    const float* __restrict__ posnn_w,
    const float* __restrict__ attnn_w, const float* __restrict__ neck_w,
    short* __restrict__ w3hi, short* __restrict__ w3lo,
    short* __restrict__ pwhi, short* __restrict__ pwlo,
    short* __restrict__ awhi, short* __restrict__ awlo,
    short* __restrict__ nwhi, short* __restrict__ nwlo)
{
    __shared__ float s1[128], s2[128];
    const int b = blockIdx.x;
    if (b < F_INPUT) {
        const int c = threadIdx.x & 127;
        const int half = threadIdx.x >> 7;
        float a1 = 0.f, a2 = 0.f;
        const int kb = half * 64;
        #pragma unroll 4
        for (int k = kb; k < kb + 64; k++) {
            float wa = attnn_w[k * H + c];
            a1 = fmaf(src_w[b * H + k], wa, a1);
            a2 = fmaf(dst_w[b * H + k], wa, a2);
        }
        if (half == 1) { s1[c] = a1; s2[c] = a2; }
        __syncthreads();
        if (half == 0) {
            a1 += s1[c]; a2 += s2[c];
            short hi, lo; int idx;
            split_bf(lin_w[b * H + c], hi, lo);
            idx = bfrag_idx(b, c, 4);       w3hi[idx] = hi; w3lo[idx] = lo;
            split_bf(a1, hi, lo);
            idx = bfrag_idx(b, 128 + c, 4); w3hi[idx] = hi; w3lo[idx] = lo;
            split_bf(a2, hi, lo);
            idx = bfrag_idx(b, 256 + c, 4); w3hi[idx] = hi; w3lo[idx] = lo;
        }
    } else if (b == F_INPUT) {
        for (int t = threadIdx.x; t < 5 * 384; t += 256) {
            int k = F_INPUT + t / 384, c = t % 384;
            int idx = bfrag_idx(k, c, 4);
            w3hi[idx] = 0; w3lo[idx] = 0;
        }
    } else if (b == F_INPUT + 1) {
        // posnn pack: 2048 entries, K16=1
        for (int idx = threadIdx.x; idx < 2048; idx += 256) {
            int kk = idx & 7; int t = idx >> 3;
            int l2 = t & 31; t >>= 5;
            int hb = t & 1;  t >>= 1;
            int ct = t;                       // 0..3
            int k = hb * 8 + kk, c = ct * 32 + l2;
            float wv = (k < 6) ? posnn_w[k * H + c] : 0.f;
            short hi, lo; split_bf(wv, hi, lo);
            pwhi[idx] = hi; pwlo[idx] = lo;
        }
    } else if (b < F_INPUT + 2 + 64) {
        int idx = (b - F_INPUT - 2) * 256 + threadIdx.x;
        int kk = idx & 7; int t = idx >> 3;
        int l2 = t & 31; t >>= 5;
        int hb = t & 1;  t >>= 1;
        int s  = t & 7;  t >>= 3;
        int c = t * 32 + l2, k = s * 16 + hb * 8 + kk;
        short hi, lo; split_bf(attnn_w[k * H + c], hi, lo);
        awhi[idx] = hi; awlo[idx] = lo;
    } else {
        int idx = (b - F_INPUT - 2 - 64) * 256 + threadIdx.x;
        int kk = idx & 7; int t = idx >> 3;
        int l2 = t & 31; t >>= 5;
        int hb = t & 1;  t >>= 1;
        int s  = t & 7;  t >>= 3;
        int c = t * 32 + l2, k = s * 16 + hb * 8 + kk;
        short hi, lo; split_bf(neck_w[k * NECK + c], hi, lo);
        nwhi[idx] = hi; nwlo[idx] = lo;
    }
}

// ---------------------------------------------------------------------------
// Kernel A: proj via MFMA. R14 structure (768 threads, 12 waves = 12 ct
// tiles, 1 ct/wave) + setprio around the MFMA cluster.
// ---------------------------------------------------------------------------
__global__ __launch_bounds__(768) void proj_kernel(
    const float* __restrict__ x, const float* __restrict__ lin_b,
    const short* __restrict__ w3hi, const short* __restrict__ w3lo,
    float2* __restrict__ vx, float* __restrict__ xdW)
{
    const int n0 = blockIdx.x * 32;
    const int tid = threadIdx.x;
    const int ct = tid >> 6;              // wave = ct tile, 0..11
    const int lane = tid & 63;
    const int hf = lane >> 5;
    const int ln = lane & 31;

    __shared__ __align__(16) short xhi[32][XPITCH];
    __shared__ __align__(16) short xlo[32][XPITCH];

    for (int idx = tid; idx < 32 * F_INPUT; idx += 768) {
        int n = idx / F_INPUT, k = idx - n * F_INPUT;
        short hi, lo; split_bf(x[n0 * F_INPUT + idx], hi, lo);
        xhi[n][k] = hi; xlo[n][k] = lo;
    }
    if (tid < 32 * 5) {
        int n = tid / 5, k = F_INPUT + tid % 5;
        xhi[n][k] = 0; xlo[n][k] = 0;
    }
    __syncthreads();

    f32x16 acc;
    #pragma unroll
    for (int r = 0; r < 16; r++) acc[r] = 0.f;

    __builtin_amdgcn_s_setprio(1);
    #pragma unroll
    for (int s = 0; s < 4; s++) {
        bf16x8 ah = *(const bf16x8*)&xhi[ln][s * 16 + hf * 8];
        bf16x8 al = *(const bf16x8*)&xlo[ln][s * 16 + hf * 8];
        const int boff = (((ct * 4 + s) * 2 + hf) * 32 + ln) * 8;
        bf16x8 bh = *(const bf16x8*)&w3hi[boff];
        bf16x8 bl = *(const bf16x8*)&w3lo[boff];
        acc = __builtin_amdgcn_mfma_f32_32x32x16_bf16(ah, bl, acc, 0, 0, 0);
        acc = __builtin_amdgcn_mfma_f32_32x32x16_bf16(al, bh, acc, 0, 0, 0);
        acc = __builtin_amdgcn_mfma_f32_32x32x16_bf16(ah, bh, acc, 0, 0, 0);
    }
    __builtin_amdgcn_s_setprio(0);

    const int tpl = ct >> 2;              // output plane 0..2
    const int c = (ct & 3) * 32 + ln;
    if (tpl == 0) {
        const float lb = lin_b[c];
        #pragma unroll
        for (int r = 0; r < 16; r++) {
            int node = n0 + (r & 3) + 8 * (r >> 2) + 4 * hf;
            ((float*)&vx[node * H + c])[1] = acc[r] + lb;   // vx.y = v
        }
    } else if (tpl == 1) {
        #pragma unroll
        for (int r = 0; r < 16; r++) {
            int node = n0 + (r & 3) + 8 * (r >> 2) + 4 * hf;
            ((float*)&vx[node * H + c])[0] = acc[r];        // vx.x = a_src
        }
    } else {
        #pragma unroll
        for (int r = 0; r < 16; r++) {
            int node = n0 + (r & 3) + 8 * (r >> 2) + 4 * hf;
            xdW[node * H + c] = acc[r];
        }
    }
}

// ---------------------------------------------------------------------------
// Kernel B: edge stage. R16: 4 nodes per block (grid 2048).
// Rationale: R15 proved edge is ISSUE-bound, not occupancy-bound (occ 38->46
// gave 0). So amortize per-block costs over 2x nodes with zero added work:
// attnn B-frag global loads per node halved, barriers per node halved,
// staging parallelism doubled. LDS 43.4 KB -> 3 blocks/CU cap (occupancy
// sacrifice is free per R15's null). (256,3): reg cap ~170 vs ~135 live.
// Revert trigger: WRITE_SIZE > 10 MB (spill).
// ---------------------------------------------------------------------------
__global__ __launch_bounds__(256, 3) void edge_kernel(
    const float* __restrict__ pos, const float* __restrict__ normal,
    const int* __restrict__ src,
    const float2* __restrict__ vx, const float* __restrict__ xdW,
    const float* __restrict__ posnn_b, const float* __restrict__ posnn_g,
    const float* __restrict__ posnn_bb,
    const float* __restrict__ attnn_b,
    const float* __restrict__ attnn_g, const float* __restrict__ attnn_bb,
    const short* __restrict__ pwhi, const short* __restrict__ pwlo,
    const short* __restrict__ awhi, const short* __restrict__ awlo,
    unsigned* __restrict__ h2)
{
    // bijective chunked swizzle: 2048 blocks, 8 XCDs, 256 blocks/chunk
    const int bid = blockIdx.x;
    const int swz = (bid & 7) * 256 + (bid >> 3);
    const int i0 = swz * 4;
    const int tid = threadIdx.x;
    const int wave = tid >> 6;
    const int lane = tid & 63;
    const int hf = lane >> 5;
    const int ln = lane & 31;

    __shared__ int srcs[4][K];
    __shared__ __align__(16) short relh[128][16];
    __shared__ __align__(16) short rell[128][16];
    __shared__ __align__(16) short dhi[128][DPITCH];

    if (tid < 128) {
        int n = tid >> 5, jj = tid & 31;
        int i = i0 + n;
        int s = src[i * K + jj];
        srcs[n][jj] = s;
        short h_, l_;
        #pragma unroll
        for (int k = 0; k < 3; k++) {
            split_bf(pos[i * 3 + k] - pos[s * 3 + k], h_, l_);
            relh[tid][k] = h_; rell[tid][k] = l_;
            split_bf(normal[i * 3 + k] - normal[s * 3 + k], h_, l_);
            relh[tid][k + 3] = h_; rell[tid][k + 3] = l_;
        }
        #pragma unroll
        for (int k = 6; k < 16; k++) { relh[tid][k] = 0; rell[tid][k] = 0; }
    }

    // per-channel constants (c = cc for this lane)
    const int cc = wave * 32 + ln;
    const float ps  = posnn_g[cc] * rsqrtf(1.f + EPS_BN);
    const float pbn = fmaf(posnn_b[cc], ps, posnn_bb[cc]);
    const float as_ = attnn_g[cc] * rsqrtf(1.f + EPS_BN);
    const float abb = attnn_bb[cc];
    const float ab  = attnn_b[cc];

    // posnn B-frag (K16=1, ct=wave)
    const bf16x8 pbh = *(const bf16x8*)&pwhi[((wave * 2 + hf) * 32 + ln) * 8];
    const bf16x8 pbl = *(const bf16x8*)&pwlo[((wave * 2 + hf) * 32 + ln) * 8];

    // hoist the per-node alpha bases (hides L2 latency under delta phase)
    float base[4];
    #pragma unroll
    for (int n = 0; n < 4; n++) base[n] = xdW[(i0 + n) * H + cc] + ab;

    __syncthreads();

    // ---- delta via MFMA for all 4 nodes; bf16-hi delta stored to LDS
    #pragma unroll
    for (int n = 0; n < 4; n++) {
        bf16x8 ah = *(const bf16x8*)&relh[32 * n + ln][hf * 8];
        bf16x8 al = *(const bf16x8*)&rell[32 * n + ln][hf * 8];
        f32x16 da;
        #pragma unroll
        for (int r = 0; r < 16; r++) da[r] = 0.f;
        da = __builtin_amdgcn_mfma_f32_32x32x16_bf16(ah, pbl, da, 0, 0, 0);
        da = __builtin_amdgcn_mfma_f32_32x32x16_bf16(al, pbh, da, 0, 0, 0);
        da = __builtin_amdgcn_mfma_f32_32x32x16_bf16(ah, pbh, da, 0, 0, 0);
        #pragma unroll
        for (int r = 0; r < 16; r++) {
            int j = (r & 3) + 8 * (r >> 2) + 4 * hf;
            float d = fmaxf(fmaf(da[r], ps, pbn), 0.f);
            dhi[32 * n + j][cc] = (short)(__float_as_uint(d) >> 16);
        }
    }
    __syncthreads();

    // ---- attnn MFMA: s-loop outer; ONE B-frag load feeds 4 nodes.
    const short* whb = awhi + wave * 8 * 2 * 32 * 8;
    const short* wlb = awlo + wave * 8 * 2 * 32 * 8;

    f32x16 acc[4];
    #pragma unroll
    for (int n = 0; n < 4; n++)
        #pragma unroll
        for (int r = 0; r < 16; r++) acc[n][r] = base[n];

    __builtin_amdgcn_s_setprio(1);
    #pragma unroll
    for (int s = 0; s < 8; s++) {
        const int boff = ((s * 2 + hf) * 32 + ln) * 8;
        bf16x8 bh = *(const bf16x8*)&whb[boff];
        bf16x8 bl = *(const bf16x8*)&wlb[boff];
        #pragma unroll
        for (int n = 0; n < 4; n++) {
            bf16x8 ah = *(const bf16x8*)&dhi[32 * n + ln][s * 16 + hf * 8];
            acc[n] = __builtin_amdgcn_mfma_f32_32x32x16_bf16(ah, bl, acc[n], 0, 0, 0);
            acc[n] = __builtin_amdgcn_mfma_f32_32x32x16_bf16(ah, bh, acc[n], 0, 0, 0);
        }
    }
    __builtin_amdgcn_s_setprio(0);

    // ---- softmax epilogue per node (gathers issued here; 16 in flight)
    #pragma unroll
    for (int n = 0; n < 4; n++) {
        const int i = i0 + n;
        float2 gvn[16];
        #pragma unroll
        for (int r = 0; r < 16; r++) {
            int j = (r & 3) + 8 * (r >> 2) + 4 * hf;
            gvn[r] = vx[srcs[n][j] * H + cc];
        }
        float a[16], vv[16];
        #pragma unroll
        for (int r = 0; r < 16; r++) {
            int j = (r & 3) + 8 * (r >> 2) + 4 * hf;
            unsigned dh = (unsigned short)dhi[32 * n + j][cc];
            float av = fmaxf(fmaf(acc[n][r] - gvn[r].x, as_, abb), 0.f);
            a[r] = av;
            vv[r] = gvn[r].y + __uint_as_float(dh << 16);
        }
        // depth-4 max tree (all a[] >= 0 from relu)
        float m01 = fmaxf(a[0], a[1]),  m23 = fmaxf(a[2], a[3]);
        float m45 = fmaxf(a[4], a[5]),  m67 = fmaxf(a[6], a[7]);
        float m89 = fmaxf(a[8], a[9]),  mab = fmaxf(a[10], a[11]);
        float mcd = fmaxf(a[12], a[13]), mef = fmaxf(a[14], a[15]);
        float m0123 = fmaxf(m01, m23), m4567 = fmaxf(m45, m67);
        float m89ab = fmaxf(m89, mab), mcdef = fmaxf(mcd, mef);
        float m = fmaxf(fmaxf(m0123, m4567), fmaxf(m89ab, mcdef));
        m = fmaxf(m, __shfl_xor(m, 32, 64));

        float dac0 = 0.f, dac1 = 0.f, dac2 = 0.f, dac3 = 0.f;
        float hac0 = 0.f, hac1 = 0.f, hac2 = 0.f, hac3 = 0.f;
        #pragma unroll
        for (int r = 0; r < 16; r += 4) {
            float e0 = __expf(a[r + 0] - m);
            float e1 = __expf(a[r + 1] - m);
            float e2 = __expf(a[r + 2] - m);
            float e3 = __expf(a[r + 3] - m);
            dac0 += e0; dac1 += e1; dac2 += e2; dac3 += e3;
            hac0 = fmaf(e0, vv[r + 0], hac0);
            hac1 = fmaf(e1, vv[r + 1], hac1);
            hac2 = fmaf(e2, vv[r + 2], hac2);
            hac3 = fmaf(e3, vv[r + 3], hac3);
        }
        float den = (dac0 + dac1) + (dac2 + dac3);
        float hsum = (hac0 + hac1) + (hac2 + hac3);
        den += __shfl_xor(den, 32, 64);
        hsum += __shfl_xor(hsum, 32, 64);
        hsum *= 1.f / (den + 1e-16f);
        if (hf == 0) {
            unsigned u = __float_as_uint(hsum);
            unsigned hib = u & 0xffff0000u;
            unsigned lo = __float_as_uint(hsum - __uint_as_float(hib)) >> 16;
            h2[i * H + cc] = (lo << 16) | (u >> 16);
        }
    }
}

// ---------------------------------------------------------------------------
// Kernel C (fused): neck MFMA + bn_relu + residue max-pool + head.
// R14 structure (1024 threads, 16 waves, 1 ct/wave, mlp1 16-way k-split)
// + setprio around the MFMA cluster.
// ---------------------------------------------------------------------------
__global__ __launch_bounds__(1024) void neck_head_kernel(
    const unsigned* __restrict__ h2,
    const short* __restrict__ nwhi, const short* __restrict__ nwlo,
    const float* __restrict__ neck_b, const float* __restrict__ neck_g,
    const float* __restrict__ neck_bb,
    const float* __restrict__ mask_t,
    const float* __restrict__ mlp1_w, const float* __restrict__ mlp1_b,
    const float* __restrict__ mlp1_g, const float* __restrict__ mlp1_bb,
    const float* __restrict__ mlp2_w, const float* __restrict__ mlp2_b,
    float* __restrict__ out)
{
    const int blk = blockIdx.x;
    const int n0 = blk * 32;
    const int tid = threadIdx.x;
    const int wave = tid >> 6;            // 0..15
    const int lane = tid & 63;
    const int hf = lane >> 5;
    const int ln = lane & 31;

    __shared__ __align__(16) short a_hi[32][DPITCH];
    __shared__ __align__(16) short a_lo[32][DPITCH];
    __shared__ float gfeat_l[4][NECK];
    __shared__ float red_l[16][4][256];

    for (int d = tid; d < 32 * H; d += 1024) {
        unsigned u = h2[(n0 + (d >> 7)) * H + (d & 127)];
        a_hi[d >> 7][d & 127] = (short)(u & 0xffffu);
        a_lo[d >> 7][d & 127] = (short)(u >> 16);
    }
    __syncthreads();

    f32x16 acc;
    #pragma unroll
    for (int r = 0; r < 16; r++) acc[r] = 0.f;

    const int ct = wave;                  // 1 ct tile per wave
    __builtin_amdgcn_s_setprio(1);
    #pragma unroll
    for (int s = 0; s < 8; s++) {
        bf16x8 ah = *(const bf16x8*)&a_hi[ln][s * 16 + hf * 8];
        bf16x8 al = *(const bf16x8*)&a_lo[ln][s * 16 + hf * 8];
        const int boff = (((ct * 8 + s) * 2 + hf) * 32 + ln) * 8;
        bf16x8 bh = *(const bf16x8*)&nwhi[boff];
        bf16x8 bl = *(const bf16x8*)&nwlo[boff];
        acc = __builtin_amdgcn_mfma_f32_32x32x16_bf16(ah, bl, acc, 0, 0, 0);
        acc = __builtin_amdgcn_mfma_f32_32x32x16_bf16(al, bh, acc, 0, 0, 0);
        acc = __builtin_amdgcn_mfma_f32_32x32x16_bf16(ah, bh, acc, 0, 0, 0);
    }
    __builtin_amdgcn_s_setprio(0);

    {
        const int c = ct * 32 + ln;
        const float s  = neck_g[c] * rsqrtf(1.f + EPS_BN);
        const float bnb = fmaf(neck_b[c], s, neck_bb[c]);
        #pragma unroll
        for (int g = 0; g < 4; g++) {
            float m = 0.f;
            #pragma unroll
            for (int q = 0; q < 4; q++)
                m = fmaxf(m, fmaf(acc[4 * g + q], s, bnb));
            m = fmaxf(m, __shfl_xor(m, 32, 64));
            if (hf == 0) gfeat_l[g][c] = m;
        }
    }
    __syncthreads();

    const int c4 = lane;
    float ph[4][4];
    #pragma unroll
    for (int g = 0; g < 4; g++)
        #pragma unroll
        for (int mm = 0; mm < 4; mm++) ph[g][mm] = 0.f;

    const int k0 = wave * 32;             // 32 k per wave
    for (int k = 0; k < 32; k += 4) {
        float4 gv[4];
        #pragma unroll
        for (int g = 0; g < 4; g++) gv[g] = *(const float4*)&gfeat_l[g][k0 + k];
        #pragma unroll
        for (int kk = 0; kk < 4; kk++) {
            float w0 = mlp1_w[(k0 + k + kk) * 256 + c4];
            float w1 = mlp1_w[(k0 + k + kk) * 256 + c4 + 64];
            float w2 = mlp1_w[(k0 + k + kk) * 256 + c4 + 128];
            float w3 = mlp1_w[(k0 + k + kk) * 256 + c4 + 192];
            #pragma unroll
            for (int g = 0; g < 4; g++) {
                float gvk = (&gv[g].x)[kk];
                ph[g][0] = fmaf(gvk, w0, ph[g][0]);
                ph[g][1] = fmaf(gvk, w1, ph[g][1]);
                ph[g][2] = fmaf(gvk, w2, ph[g][2]);
                ph[g][3] = fmaf(gvk, w3, ph[g][3]);
            }
        }
    }
    #pragma unroll
    for (int g = 0; g < 4; g++)
        #pragma unroll
        for (int mm = 0; mm < 4; mm++)
            red_l[wave][g][c4 + 64 * mm] = ph[g][mm];
    __syncthreads();

    if (wave < 4) {
        const int g = wave;
        float part = 0.f;
        #pragma unroll
        for (int mm = 0; mm < 4; mm++) {
            const int c = c4 + 64 * mm;
            float sum = mlp1_b[c];
            #pragma unroll
            for (int w = 0; w < 16; w++) sum += red_l[w][g][c];
            float s = mlp1_g[c] * rsqrtf(1.f + EPS_BN);
            float val = fmaxf(fmaf(sum, s, mlp1_bb[c]), 0.f);
            part = fmaf(val, mlp2_w[c], part);
        }
        #pragma unroll
        for (int off = 32; off > 0; off >>= 1) part += __shfl_xor(part, off, 64);
        if (lane == 0) {
            const int gg = blk * 4 + g;
            float mm = mask_t[gg * GPER];
            #pragma unroll
            for (int n = 1; n < GPER; n++) mm = fmaxf(mm, mask_t[gg * GPER + n]);
            out[gg] = (mm == 1.0f) ? (part + mlp2_b[0]) : 0.f;
        }
    }
}

// ---------------------------------------------------------------------------
extern "C" void kernel_launch(void* const* d_in, const int* in_sizes, int n_in,
                              void* d_out, int out_size, void* d_ws, size_t ws_size,
                              hipStream_t stream)
{
    const float* x        = (const float*)d_in[0];
    const float* pos      = (const float*)d_in[1];
    const float* normal   = (const float*)d_in[2];
    const float* mask_t   = (const float*)d_in[3];
    const int*   src      = (const int*)d_in[5];
    const float* lin_w    = (const float*)d_in[7];
    const float* lin_b    = (const float*)d_in[8];
    const float* src_w    = (const float*)d_in[9];
    const float* dst_w    = (const float*)d_in[10];
    const float* posnn_w  = (const float*)d_in[11];
    const float* posnn_b  = (const float*)d_in[12];
    const float* posnn_g  = (const float*)d_in[13];
    const float* posnn_bb = (const float*)d_in[14];
    const float* attnn_w  = (const float*)d_in[15];
    const float* attnn_b  = (const float*)d_in[16];
    const float* attnn_g  = (const float*)d_in[17];
    const float* attnn_bb = (const float*)d_in[18];
    const float* neck_w   = (const float*)d_in[19];
    const float* neck_b   = (const float*)d_in[20];
    const float* neck_g   = (const float*)d_in[21];
    const float* neck_bb  = (const float*)d_in[22];
    const float* mlp1_w   = (const float*)d_in[23];
    const float* mlp1_b   = (const float*)d_in[24];
    const float* mlp1_g   = (const float*)d_in[25];
    const float* mlp1_bb  = (const float*)d_in[26];
    const float* mlp2_w   = (const float*)d_in[27];
    const float* mlp2_b   = (const float*)d_in[28];

    float* ws = (float*)d_ws;
    float2*   vx   = (float2*)ws;                              // N*H float2
    float*    xdW  = (float*)(vx + (size_t)N_NODES * H);       // N*H
    unsigned* h2   = (unsigned*)(xdW + (size_t)N_NODES * H);   // N*H
    short*    w3hi = (short*)(h2 + (size_t)N_NODES * H);       // 24576
    short*    w3lo = w3hi + 24576;
    short*    pwhi = w3lo + 24576;                             // 2048
    short*    pwlo = pwhi + 2048;
    short*    awhi = pwlo + 2048;                              // 16384
    short*    awlo = awhi + H * H;
    short*    nwhi = awlo + H * H;                             // 65536
    short*    nwlo = nwhi + H * NECK;

    prep_kernel<<<F_INPUT + 2 + 64 + 256, 256, 0, stream>>>(
        lin_w, src_w, dst_w, posnn_w, attnn_w, neck_w,
        w3hi, w3lo, pwhi, pwlo, awhi, awlo, nwhi, nwlo);
    proj_kernel<<<N_NODES / 32, 768, 0, stream>>>(x, lin_b, w3hi, w3lo, vx, xdW);
    edge_kernel<<<N_NODES / 4, 256, 0, stream>>>(pos, normal, src, vx, xdW,
                                                 posnn_b, posnn_g, posnn_bb,
                                                 attnn_b, attnn_g, attnn_bb,
                                                 pwhi, pwlo, awhi, awlo, h2);
    neck_head_kernel<<<N_NODES / 32, 1024, 0, stream>>>(
        h2, nwhi, nwlo, neck_b, neck_g, neck_bb, mask_t,
        mlp1_w, mlp1_b, mlp1_g, mlp1_bb, mlp2_w, mlp2_b, (float*)d_out);
}

// Round 14
// 169.805 us; speedup vs baseline: 1.0405x; 1.0209x over previous
//
#include <hip/hip_runtime.h>
#include <hip/hip_bf16.h>
#include <cmath>

#define N_NODES 8192
#define F_INPUT 59
#define H 128
#define K 32
#define NECK 512
#define GPER 8
#define NG 1024
#define EPS_BN 1e-5f
#define DPITCH 136   // bf16 row pitch (272 B, 16B-aligned)
#define XPITCH 72    // proj x-plane pitch (144 B, 16B-aligned)

typedef short bf16x8 __attribute__((ext_vector_type(8)));
typedef float f32x16 __attribute__((ext_vector_type(16)));

// truncation hi/lo split
__device__ __forceinline__ void split_bf(float v, short& hi, short& lo) {
    unsigned u = __float_as_uint(v);
    float hif = __uint_as_float(u & 0xffff0000u);
    hi = (short)(u >> 16);
    lo = (short)(__float_as_uint(v - hif) >> 16);
}

// B-frag flat index for 32x32x16: c = ct*32+ln, k = s*16+hf*8+kk
__device__ __forceinline__ int bfrag_idx(int k, int c, int k16) {
    int ct = c >> 5, ln = c & 31;
    int s = k >> 4, hf = (k >> 3) & 1, kk = k & 7;
    return ((((ct * k16 + s) * 2 + hf) * 32 + ln) * 8 + kk);
}

// ---------------------------------------------------------------------------
// Prep (fused) -- R15: unroll-4 on the serial k loop.
// ---------------------------------------------------------------------------
__global__ __launch_bounds__(256) void prep_kernel(
    const float* __restrict__ lin_w,
    const float* __restrict__ src_w, const float* __restrict__ dst_w,
    const float* __restrict__ posnn_w,
    const float* __restrict__ attnn_w, const float* __restrict__ neck_w,
    short* __restrict__ w3hi, short* __restrict__ w3lo,
    short* __restrict__ pwhi, short* __restrict__ pwlo,
    short* __restrict__ awhi, short* __restrict__ awlo,
    short* __restrict__ nwhi, short* __restrict__ nwlo)
{
    __shared__ float s1[128], s2[128];
    const int b = blockIdx.x;
    if (b < F_INPUT) {
        const int c = threadIdx.x & 127;
        const int half = threadIdx.x >> 7;
        float a1 = 0.f, a2 = 0.f;
        const int kb = half * 64;
        #pragma unroll 4
        for (int k = kb; k < kb + 64; k++) {
            float wa = attnn_w[k * H + c];
            a1 = fmaf(src_w[b * H + k], wa, a1);
            a2 = fmaf(dst_w[b * H + k], wa, a2);
        }
        if (half == 1) { s1[c] = a1; s2[c] = a2; }
        __syncthreads();
        if (half == 0) {
            a1 += s1[c]; a2 += s2[c];
            short hi, lo; int idx;
            split_bf(lin_w[b * H + c], hi, lo);
            idx = bfrag_idx(b, c, 4);       w3hi[idx] = hi; w3lo[idx] = lo;
            split_bf(a1, hi, lo);
            idx = bfrag_idx(b, 128 + c, 4); w3hi[idx] = hi; w3lo[idx] = lo;
            split_bf(a2, hi, lo);
            idx = bfrag_idx(b, 256 + c, 4); w3hi[idx] = hi; w3lo[idx] = lo;
        }
    } else if (b == F_INPUT) {
        for (int t = threadIdx.x; t < 5 * 384; t += 256) {
            int k = F_INPUT + t / 384, c = t % 384;
            int idx = bfrag_idx(k, c, 4);
            w3hi[idx] = 0; w3lo[idx] = 0;
        }
    } else if (b == F_INPUT + 1) {
        // posnn pack: 2048 entries, K16=1
        for (int idx = threadIdx.x; idx < 2048; idx += 256) {
            int kk = idx & 7; int t = idx >> 3;
            int l2 = t & 31; t >>= 5;
            int hb = t & 1;  t >>= 1;
            int ct = t;                       // 0..3
            int k = hb * 8 + kk, c = ct * 32 + l2;
            float wv = (k < 6) ? posnn_w[k * H + c] : 0.f;
            short hi, lo; split_bf(wv, hi, lo);
            pwhi[idx] = hi; pwlo[idx] = lo;
        }
    } else if (b < F_INPUT + 2 + 64) {
        int idx = (b - F_INPUT - 2) * 256 + threadIdx.x;
        int kk = idx & 7; int t = idx >> 3;
        int l2 = t & 31; t >>= 5;
        int hb = t & 1;  t >>= 1;
        int s  = t & 7;  t >>= 3;
        int c = t * 32 + l2, k = s * 16 + hb * 8 + kk;
        short hi, lo; split_bf(attnn_w[k * H + c], hi, lo);
        awhi[idx] = hi; awlo[idx] = lo;
    } else {
        int idx = (b - F_INPUT - 2 - 64) * 256 + threadIdx.x;
        int kk = idx & 7; int t = idx >> 3;
        int l2 = t & 31; t >>= 5;
        int hb = t & 1;  t >>= 1;
        int s  = t & 7;  t >>= 3;
        int c = t * 32 + l2, k = s * 16 + hb * 8 + kk;
        short hi, lo; split_bf(neck_w[k * NECK + c], hi, lo);
        nwhi[idx] = hi; nwlo[idx] = lo;
    }
}

// ---------------------------------------------------------------------------
// Kernel A: proj via MFMA. 768 threads, 12 waves = 12 ct tiles, 1 ct/wave;
// setprio around the MFMA cluster.
// ---------------------------------------------------------------------------
__global__ __launch_bounds__(768) void proj_kernel(
    const float* __restrict__ x, const float* __restrict__ lin_b,
    const short* __restrict__ w3hi, const short* __restrict__ w3lo,
    float2* __restrict__ vx, float* __restrict__ xdW)
{
    const int n0 = blockIdx.x * 32;
    const int tid = threadIdx.x;
    const int ct = tid >> 6;              // wave = ct tile, 0..11
    const int lane = tid & 63;
    const int hf = lane >> 5;
    const int ln = lane & 31;

    __shared__ __align__(16) short xhi[32][XPITCH];
    __shared__ __align__(16) short xlo[32][XPITCH];

    for (int idx = tid; idx < 32 * F_INPUT; idx += 768) {
        int n = idx / F_INPUT, k = idx - n * F_INPUT;
        short hi, lo; split_bf(x[n0 * F_INPUT + idx], hi, lo);
        xhi[n][k] = hi; xlo[n][k] = lo;
    }
    if (tid < 32 * 5) {
        int n = tid / 5, k = F_INPUT + tid % 5;
        xhi[n][k] = 0; xlo[n][k] = 0;
    }
    __syncthreads();

    f32x16 acc;
    #pragma unroll
    for (int r = 0; r < 16; r++) acc[r] = 0.f;

    __builtin_amdgcn_s_setprio(1);
    #pragma unroll
    for (int s = 0; s < 4; s++) {
        bf16x8 ah = *(const bf16x8*)&xhi[ln][s * 16 + hf * 8];
        bf16x8 al = *(const bf16x8*)&xlo[ln][s * 16 + hf * 8];
        const int boff = (((ct * 4 + s) * 2 + hf) * 32 + ln) * 8;
        bf16x8 bh = *(const bf16x8*)&w3hi[boff];
        bf16x8 bl = *(const bf16x8*)&w3lo[boff];
        acc = __builtin_amdgcn_mfma_f32_32x32x16_bf16(ah, bl, acc, 0, 0, 0);
        acc = __builtin_amdgcn_mfma_f32_32x32x16_bf16(al, bh, acc, 0, 0, 0);
        acc = __builtin_amdgcn_mfma_f32_32x32x16_bf16(ah, bh, acc, 0, 0, 0);
    }
    __builtin_amdgcn_s_setprio(0);

    const int tpl = ct >> 2;              // output plane 0..2
    const int c = (ct & 3) * 32 + ln;
    if (tpl == 0) {
        const float lb = lin_b[c];
        #pragma unroll
        for (int r = 0; r < 16; r++) {
            int node = n0 + (r & 3) + 8 * (r >> 2) + 4 * hf;
            ((float*)&vx[node * H + c])[1] = acc[r] + lb;   // vx.y = v
        }
    } else if (tpl == 1) {
        #pragma unroll
        for (int r = 0; r < 16; r++) {
            int node = n0 + (r & 3) + 8 * (r >> 2) + 4 * hf;
            ((float*)&vx[node * H + c])[0] = acc[r];        // vx.x = a_src
        }
    } else {
        #pragma unroll
        for (int r = 0; r < 16; r++) {
            int node = n0 + (r & 3) + 8 * (r >> 2) + 4 * hf;
            xdW[node * H + c] = acc[r];
        }
    }
}

// ---------------------------------------------------------------------------
// Kernel B: edge stage. R16 4-node structure; R17: attnn B-lo plane dropped
// in the MFMA loop (alpha's delta-term tolerates bf16 weights; xdW and
// a_src terms keep full precision from proj). 1 MFMA per s per node
// (was 2) and no wlb loads -> halves attnn issue traffic.
// Revert trigger: absmax > 0.1.
// ---------------------------------------------------------------------------
__global__ __launch_bounds__(256, 3) void edge_kernel(
    const float* __restrict__ pos, const float* __restrict__ normal,
    const int* __restrict__ src,
    const float2* __restrict__ vx, const float* __restrict__ xdW,
    const float* __restrict__ posnn_b, const float* __restrict__ posnn_g,
    const float* __restrict__ posnn_bb,
    const float* __restrict__ attnn_b,
    const float* __restrict__ attnn_g, const float* __restrict__ attnn_bb,
    const short* __restrict__ pwhi, const short* __restrict__ pwlo,
    const short* __restrict__ awhi, const short* __restrict__ awlo,
    unsigned* __restrict__ h2)
{
    // bijective chunked swizzle: 2048 blocks, 8 XCDs, 256 blocks/chunk
    const int bid = blockIdx.x;
    const int swz = (bid & 7) * 256 + (bid >> 3);
    const int i0 = swz * 4;
    const int tid = threadIdx.x;
    const int wave = tid >> 6;
    const int lane = tid & 63;
    const int hf = lane >> 5;
    const int ln = lane & 31;

    __shared__ int srcs[4][K];
    __shared__ __align__(16) short relh[128][16];
    __shared__ __align__(16) short rell[128][16];
    __shared__ __align__(16) short dhi[128][DPITCH];

    if (tid < 128) {
        int n = tid >> 5, jj = tid & 31;
        int i = i0 + n;
        int s = src[i * K + jj];
        srcs[n][jj] = s;
        short h_, l_;
        #pragma unroll
        for (int k = 0; k < 3; k++) {
            split_bf(pos[i * 3 + k] - pos[s * 3 + k], h_, l_);
            relh[tid][k] = h_; rell[tid][k] = l_;
            split_bf(normal[i * 3 + k] - normal[s * 3 + k], h_, l_);
            relh[tid][k + 3] = h_; rell[tid][k + 3] = l_;
        }
        #pragma unroll
        for (int k = 6; k < 16; k++) { relh[tid][k] = 0; rell[tid][k] = 0; }
    }

    // per-channel constants (c = cc for this lane)
    const int cc = wave * 32 + ln;
    const float ps  = posnn_g[cc] * rsqrtf(1.f + EPS_BN);
    const float pbn = fmaf(posnn_b[cc], ps, posnn_bb[cc]);
    const float as_ = attnn_g[cc] * rsqrtf(1.f + EPS_BN);
    const float abb = attnn_bb[cc];
    const float ab  = attnn_b[cc];

    // posnn B-frag (K16=1, ct=wave)
    const bf16x8 pbh = *(const bf16x8*)&pwhi[((wave * 2 + hf) * 32 + ln) * 8];
    const bf16x8 pbl = *(const bf16x8*)&pwlo[((wave * 2 + hf) * 32 + ln) * 8];

    // hoist the per-node alpha bases (hides L2 latency under delta phase)
    float base[4];
    #pragma unroll
    for (int n = 0; n < 4; n++) base[n] = xdW[(i0 + n) * H + cc] + ab;

    __syncthreads();

    // ---- delta via MFMA for all 4 nodes; bf16-hi delta stored to LDS
    #pragma unroll
    for (int n = 0; n < 4; n++) {
        bf16x8 ah = *(const bf16x8*)&relh[32 * n + ln][hf * 8];
        bf16x8 al = *(const bf16x8*)&rell[32 * n + ln][hf * 8];
        f32x16 da;
        #pragma unroll
        for (int r = 0; r < 16; r++) da[r] = 0.f;
        da = __builtin_amdgcn_mfma_f32_32x32x16_bf16(ah, pbl, da, 0, 0, 0);
        da = __builtin_amdgcn_mfma_f32_32x32x16_bf16(al, pbh, da, 0, 0, 0);
        da = __builtin_amdgcn_mfma_f32_32x32x16_bf16(ah, pbh, da, 0, 0, 0);
        #pragma unroll
        for (int r = 0; r < 16; r++) {
            int j = (r & 3) + 8 * (r >> 2) + 4 * hf;
            float d = fmaxf(fmaf(da[r], ps, pbn), 0.f);
            dhi[32 * n + j][cc] = (short)(__float_as_uint(d) >> 16);
        }
    }
    __syncthreads();

    // ---- attnn MFMA: s-loop outer; ONE bh-frag load feeds 4 nodes,
    //      1 MFMA per s per node (B-lo dropped).
    const short* whb = awhi + wave * 8 * 2 * 32 * 8;

    f32x16 acc[4];
    #pragma unroll
    for (int n = 0; n < 4; n++)
        #pragma unroll
        for (int r = 0; r < 16; r++) acc[n][r] = base[n];

    __builtin_amdgcn_s_setprio(1);
    #pragma unroll
    for (int s = 0; s < 8; s++) {
        const int boff = ((s * 2 + hf) * 32 + ln) * 8;
        bf16x8 bh = *(const bf16x8*)&whb[boff];
        #pragma unroll
        for (int n = 0; n < 4; n++) {
            bf16x8 ah = *(const bf16x8*)&dhi[32 * n + ln][s * 16 + hf * 8];
            acc[n] = __builtin_amdgcn_mfma_f32_32x32x16_bf16(ah, bh, acc[n], 0, 0, 0);
        }
    }
    __builtin_amdgcn_s_setprio(0);

    // ---- softmax epilogue per node (gathers issued here; 16 in flight)
    #pragma unroll
    for (int n = 0; n < 4; n++) {
        const int i = i0 + n;
        float2 gvn[16];
        #pragma unroll
        for (int r = 0; r < 16; r++) {
            int j = (r & 3) + 8 * (r >> 2) + 4 * hf;
            gvn[r] = vx[srcs[n][j] * H + cc];
        }
        float a[16], vv[16];
        #pragma unroll
        for (int r = 0; r < 16; r++) {
            int j = (r & 3) + 8 * (r >> 2) + 4 * hf;
            unsigned dh = (unsigned short)dhi[32 * n + j][cc];
            float av = fmaxf(fmaf(acc[n][r] - gvn[r].x, as_, abb), 0.f);
            a[r] = av;
            vv[r] = gvn[r].y + __uint_as_float(dh << 16);
        }
        // depth-4 max tree (all a[] >= 0 from relu)
        float m01 = fmaxf(a[0], a[1]),  m23 = fmaxf(a[2], a[3]);
        float m45 = fmaxf(a[4], a[5]),  m67 = fmaxf(a[6], a[7]);
        float m89 = fmaxf(a[8], a[9]),  mab = fmaxf(a[10], a[11]);
        float mcd = fmaxf(a[12], a[13]), mef = fmaxf(a[14], a[15]);
        float m0123 = fmaxf(m01, m23), m4567 = fmaxf(m45, m67);
        float m89ab = fmaxf(m89, mab), mcdef = fmaxf(mcd, mef);
        float m = fmaxf(fmaxf(m0123, m4567), fmaxf(m89ab, mcdef));
        m = fmaxf(m, __shfl_xor(m, 32, 64));

        float dac0 = 0.f, dac1 = 0.f, dac2 = 0.f, dac3 = 0.f;
        float hac0 = 0.f, hac1 = 0.f, hac2 = 0.f, hac3 = 0.f;
        #pragma unroll
        for (int r = 0; r < 16; r += 4) {
            float e0 = __expf(a[r + 0] - m);
            float e1 = __expf(a[r + 1] - m);
            float e2 = __expf(a[r + 2] - m);
            float e3 = __expf(a[r + 3] - m);
            dac0 += e0; dac1 += e1; dac2 += e2; dac3 += e3;
            hac0 = fmaf(e0, vv[r + 0], hac0);
            hac1 = fmaf(e1, vv[r + 1], hac1);
            hac2 = fmaf(e2, vv[r + 2], hac2);
            hac3 = fmaf(e3, vv[r + 3], hac3);
        }
        float den = (dac0 + dac1) + (dac2 + dac3);
        float hsum = (hac0 + hac1) + (hac2 + hac3);
        den += __shfl_xor(den, 32, 64);
        hsum += __shfl_xor(hsum, 32, 64);
        hsum *= 1.f / (den + 1e-16f);
        if (hf == 0) {
            unsigned u = __float_as_uint(hsum);
            unsigned hib = u & 0xffff0000u;
            unsigned lo = __float_as_uint(hsum - __uint_as_float(hib)) >> 16;
            h2[i * H + cc] = (lo << 16) | (u >> 16);
        }
    }
}

// ---------------------------------------------------------------------------
// Kernel C (fused): neck MFMA + bn_relu + residue max-pool + head.
// 1024 threads, 16 waves, 1 ct/wave, mlp1 16-way k-split; setprio on MFMA.
// ---------------------------------------------------------------------------
__global__ __launch_bounds__(1024) void neck_head_kernel(
    const unsigned* __restrict__ h2,
    const short* __restrict__ nwhi, const short* __restrict__ nwlo,
    const float* __restrict__ neck_b, const float* __restrict__ neck_g,
    const float* __restrict__ neck_bb,
    const float* __restrict__ mask_t,
    const float* __restrict__ mlp1_w, const float* __restrict__ mlp1_b,
    const float* __restrict__ mlp1_g, const float* __restrict__ mlp1_bb,
    const float* __restrict__ mlp2_w, const float* __restrict__ mlp2_b,
    float* __restrict__ out)
{
    const int blk = blockIdx.x;
    const int n0 = blk * 32;
    const int tid = threadIdx.x;
    const int wave = tid >> 6;            // 0..15
    const int lane = tid & 63;
    const int hf = lane >> 5;
    const int ln = lane & 31;

    __shared__ __align__(16) short a_hi[32][DPITCH];
    __shared__ __align__(16) short a_lo[32][DPITCH];
    __shared__ float gfeat_l[4][NECK];
    __shared__ float red_l[16][4][256];

    for (int d = tid; d < 32 * H; d += 1024) {
        unsigned u = h2[(n0 + (d >> 7)) * H + (d & 127)];
        a_hi[d >> 7][d & 127] = (short)(u & 0xffffu);
        a_lo[d >> 7][d & 127] = (short)(u >> 16);
    }
    __syncthreads();

    f32x16 acc;
    #pragma unroll
    for (int r = 0; r < 16; r++) acc[r] = 0.f;

    const int ct = wave;                  // 1 ct tile per wave
    __builtin_amdgcn_s_setprio(1);
    #pragma unroll
    for (int s = 0; s < 8; s++) {
        bf16x8 ah = *(const bf16x8*)&a_hi[ln][s * 16 + hf * 8];
        bf16x8 al = *(const bf16x8*)&a_lo[ln][s * 16 + hf * 8];
        const int boff = (((ct * 8 + s) * 2 + hf) * 32 + ln) * 8;
        bf16x8 bh = *(const bf16x8*)&nwhi[boff];
        bf16x8 bl = *(const bf16x8*)&nwlo[boff];
        acc = __builtin_amdgcn_mfma_f32_32x32x16_bf16(ah, bl, acc, 0, 0, 0);
        acc = __builtin_amdgcn_mfma_f32_32x32x16_bf16(al, bh, acc, 0, 0, 0);
        acc = __builtin_amdgcn_mfma_f32_32x32x16_bf16(ah, bh, acc, 0, 0, 0);
    }
    __builtin_amdgcn_s_setprio(0);

    {
        const int c = ct * 32 + ln;
        const float s  = neck_g[c] * rsqrtf(1.f + EPS_BN);
        const float bnb = fmaf(neck_b[c], s, neck_bb[c]);
        #pragma unroll
        for (int g = 0; g < 4; g++) {
            float m = 0.f;
            #pragma unroll
            for (int q = 0; q < 4; q++)
                m = fmaxf(m, fmaf(acc[4 * g + q], s, bnb));
            m = fmaxf(m, __shfl_xor(m, 32, 64));
            if (hf == 0) gfeat_l[g][c] = m;
        }
    }
    __syncthreads();

    const int c4 = lane;
    float ph[4][4];
    #pragma unroll
    for (int g = 0; g < 4; g++)
        #pragma unroll
        for (int mm = 0; mm < 4; mm++) ph[g][mm] = 0.f;

    const int k0 = wave * 32;             // 32 k per wave
    for (int k = 0; k < 32; k += 4) {
        float4 gv[4];
        #pragma unroll
        for (int g = 0; g < 4; g++) gv[g] = *(const float4*)&gfeat_l[g][k0 + k];
        #pragma unroll
        for (int kk = 0; kk < 4; kk++) {
            float w0 = mlp1_w[(k0 + k + kk) * 256 + c4];
            float w1 = mlp1_w[(k0 + k + kk) * 256 + c4 + 64];
            float w2 = mlp1_w[(k0 + k + kk) * 256 + c4 + 128];
            float w3 = mlp1_w[(k0 + k + kk) * 256 + c4 + 192];
            #pragma unroll
            for (int g = 0; g < 4; g++) {
                float gvk = (&gv[g].x)[kk];
                ph[g][0] = fmaf(gvk, w0, ph[g][0]);
                ph[g][1] = fmaf(gvk, w1, ph[g][1]);
                ph[g][2] = fmaf(gvk, w2, ph[g][2]);
                ph[g][3] = fmaf(gvk, w3, ph[g][3]);
            }
        }
    }
    #pragma unroll
    for (int g = 0; g < 4; g++)
        #pragma unroll
        for (int mm = 0; mm < 4; mm++)
            red_l[wave][g][c4 + 64 * mm] = ph[g][mm];
    __syncthreads();

    if (wave < 4) {
        const int g = wave;
        float part = 0.f;
        #pragma unroll
        for (int mm = 0; mm < 4; mm++) {
            const int c = c4 + 64 * mm;
            float sum = mlp1_b[c];
            #pragma unroll
            for (int w = 0; w < 16; w++) sum += red_l[w][g][c];
            float s = mlp1_g[c] * rsqrtf(1.f + EPS_BN);
            float val = fmaxf(fmaf(sum, s, mlp1_bb[c]), 0.f);
            part = fmaf(val, mlp2_w[c], part);
        }
        #pragma unroll
        for (int off = 32; off > 0; off >>= 1) part += __shfl_xor(part, off, 64);
        if (lane == 0) {
            const int gg = blk * 4 + g;
            float mm = mask_t[gg * GPER];
            #pragma unroll
            for (int n = 1; n < GPER; n++) mm = fmaxf(mm, mask_t[gg * GPER + n]);
            out[gg] = (mm == 1.0f) ? (part + mlp2_b[0]) : 0.f;
        }
    }
}

// ---------------------------------------------------------------------------
extern "C" void kernel_launch(void* const* d_in, const int* in_sizes, int n_in,
                              void* d_out, int out_size, void* d_ws, size_t ws_size,
                              hipStream_t stream)
{
    const float* x        = (const float*)d_in[0];
    const float* pos      = (const float*)d_in[1];
    const float* normal   = (const float*)d_in[2];
    const float* mask_t   = (const float*)d_in[3];
    const int*   src      = (const int*)d_in[5];
    const float* lin_w    = (const float*)d_in[7];
    const float* lin_b    = (const float*)d_in[8];
    const float* src_w    = (const float*)d_in[9];
    const float* dst_w    = (const float*)d_in[10];
    const float* posnn_w  = (const float*)d_in[11];
    const float* posnn_b  = (const float*)d_in[12];
    const float* posnn_g  = (const float*)d_in[13];
    const float* posnn_bb = (const float*)d_in[14];
    const float* attnn_w  = (const float*)d_in[15];
    const float* attnn_b  = (const float*)d_in[16];
    const float* attnn_g  = (const float*)d_in[17];
    const float* attnn_bb = (const float*)d_in[18];
    const float* neck_w   = (const float*)d_in[19];
    const float* neck_b   = (const float*)d_in[20];
    const float* neck_g   = (const float*)d_in[21];
    const float* neck_bb  = (const float*)d_in[22];
    const float* mlp1_w   = (const float*)d_in[23];
    const float* mlp1_b   = (const float*)d_in[24];
    const float* mlp1_g   = (const float*)d_in[25];
    const float* mlp1_bb  = (const float*)d_in[26];
    const float* mlp2_w   = (const float*)d_in[27];
    const float* mlp2_b   = (const float*)d_in[28];

    float* ws = (float*)d_ws;
    float2*   vx   = (float2*)ws;                              // N*H float2
    float*    xdW  = (float*)(vx + (size_t)N_NODES * H);       // N*H
    unsigned* h2   = (unsigned*)(xdW + (size_t)N_NODES * H);   // N*H
    short*    w3hi = (short*)(h2 + (size_t)N_NODES * H);       // 24576
    short*    w3lo = w3hi + 24576;
    short*    pwhi = w3lo + 24576;                             // 2048
    short*    pwlo = pwhi + 2048;
    short*    awhi = pwlo + 2048;                              // 16384
    short*    awlo = awhi + H * H;
    short*    nwhi = awlo + H * H;                             // 65536
    short*    nwlo = nwhi + H * NECK;

    prep_kernel<<<F_INPUT + 2 + 64 + 256, 256, 0, stream>>>(
        lin_w, src_w, dst_w, posnn_w, attnn_w, neck_w,
        w3hi, w3lo, pwhi, pwlo, awhi, awlo, nwhi, nwlo);
    proj_kernel<<<N_NODES / 32, 768, 0, stream>>>(x, lin_b, w3hi, w3lo, vx, xdW);
    edge_kernel<<<N_NODES / 4, 256, 0, stream>>>(pos, normal, src, vx, xdW,
                                                 posnn_b, posnn_g, posnn_bb,
                                                 attnn_b, attnn_g, attnn_bb,
                                                 pwhi, pwlo, awhi, awlo, h2);
    neck_head_kernel<<<N_NODES / 32, 1024, 0, stream>>>(
        h2, nwhi, nwlo, neck_b, neck_g, neck_bb, mask_t,
        mlp1_w, mlp1_b, mlp1_g, mlp1_bb, mlp2_w, mlp2_b, (float*)d_out);
}

// Round 15
// 167.826 us; speedup vs baseline: 1.0528x; 1.0118x over previous
//
#include <hip/hip_runtime.h>
#include <hip/hip_bf16.h>
#include <cmath>

#define N_NODES 8192
#define F_INPUT 59
#define H 128
#define K 32
#define NECK 512
#define GPER 8
#define NG 1024
#define EPS_BN 1e-5f
#define DPITCH 136   // bf16 row pitch (272 B, 16B-aligned)
#define XPITCH 72    // proj x-plane pitch (144 B, 16B-aligned)

typedef short bf16x8 __attribute__((ext_vector_type(8)));
typedef float f32x16 __attribute__((ext_vector_type(16)));

// truncation hi/lo split
__device__ __forceinline__ void split_bf(float v, short& hi, short& lo) {
    unsigned u = __float_as_uint(v);
    float hif = __uint_as_float(u & 0xffff0000u);
    hi = (short)(u >> 16);
    lo = (short)(__float_as_uint(v - hif) >> 16);
}

__device__ __forceinline__ short bfhi(float v) {
    return (short)(__float_as_uint(v) >> 16);
}

// B-frag flat index for 32x32x16: c = ct*32+ln, k = s*16+hf*8+kk
__device__ __forceinline__ int bfrag_idx(int k, int c, int k16) {
    int ct = c >> 5, ln = c & 31;
    int s = k >> 4, hf = (k >> 3) & 1, kk = k & 7;
    return ((((ct * k16 + s) * 2 + hf) * 32 + ln) * 8 + kk);
}

// ---------------------------------------------------------------------------
// Prep (fused) -- unroll-4 on the serial k loop.
// ---------------------------------------------------------------------------
__global__ __launch_bounds__(256) void prep_kernel(
    const float* __restrict__ lin_w,
    const float* __restrict__ src_w, const float* __restrict__ dst_w,
    const float* __restrict__ posnn_w,
    const float* __restrict__ attnn_w, const float* __restrict__ neck_w,
    short* __restrict__ w3hi, short* __restrict__ w3lo,
    short* __restrict__ pwhi, short* __restrict__ pwlo,
    short* __restrict__ awhi, short* __restrict__ awlo,
    short* __restrict__ nwhi, short* __restrict__ nwlo)
{
    __shared__ float s1[128], s2[128];
    const int b = blockIdx.x;
    if (b < F_INPUT) {
        const int c = threadIdx.x & 127;
        const int half = threadIdx.x >> 7;
        float a1 = 0.f, a2 = 0.f;
        const int kb = half * 64;
        #pragma unroll 4
        for (int k = kb; k < kb + 64; k++) {
            float wa = attnn_w[k * H + c];
            a1 = fmaf(src_w[b * H + k], wa, a1);
            a2 = fmaf(dst_w[b * H + k], wa, a2);
        }
        if (half == 1) { s1[c] = a1; s2[c] = a2; }
        __syncthreads();
        if (half == 0) {
            a1 += s1[c]; a2 += s2[c];
            short hi, lo; int idx;
            split_bf(lin_w[b * H + c], hi, lo);
            idx = bfrag_idx(b, c, 4);       w3hi[idx] = hi; w3lo[idx] = lo;
            split_bf(a1, hi, lo);
            idx = bfrag_idx(b, 128 + c, 4); w3hi[idx] = hi; w3lo[idx] = lo;
            split_bf(a2, hi, lo);
            idx = bfrag_idx(b, 256 + c, 4); w3hi[idx] = hi; w3lo[idx] = lo;
        }
    } else if (b == F_INPUT) {
        for (int t = threadIdx.x; t < 5 * 384; t += 256) {
            int k = F_INPUT + t / 384, c = t % 384;
            int idx = bfrag_idx(k, c, 4);
            w3hi[idx] = 0; w3lo[idx] = 0;
        }
    } else if (b == F_INPUT + 1) {
        // posnn pack: 2048 entries, K16=1
        for (int idx = threadIdx.x; idx < 2048; idx += 256) {
            int kk = idx & 7; int t = idx >> 3;
            int l2 = t & 31; t >>= 5;
            int hb = t & 1;  t >>= 1;
            int ct = t;                       // 0..3
            int k = hb * 8 + kk, c = ct * 32 + l2;
            float wv = (k < 6) ? posnn_w[k * H + c] : 0.f;
            short hi, lo; split_bf(wv, hi, lo);
            pwhi[idx] = hi; pwlo[idx] = lo;
        }
    } else if (b < F_INPUT + 2 + 64) {
        int idx = (b - F_INPUT - 2) * 256 + threadIdx.x;
        int kk = idx & 7; int t = idx >> 3;
        int l2 = t & 31; t >>= 5;
        int hb = t & 1;  t >>= 1;
        int s  = t & 7;  t >>= 3;
        int c = t * 32 + l2, k = s * 16 + hb * 8 + kk;
        short hi, lo; split_bf(attnn_w[k * H + c], hi, lo);
        awhi[idx] = hi; awlo[idx] = lo;
    } else {
        int idx = (b - F_INPUT - 2 - 64) * 256 + threadIdx.x;
        int kk = idx & 7; int t = idx >> 3;
        int l2 = t & 31; t >>= 5;
        int hb = t & 1;  t >>= 1;
        int s  = t & 7;  t >>= 3;
        int c = t * 32 + l2, k = s * 16 + hb * 8 + kk;
        short hi, lo; split_bf(neck_w[k * NECK + c], hi, lo);
        nwhi[idx] = hi; nwlo[idx] = lo;
    }
}

// ---------------------------------------------------------------------------
// Kernel A: proj via MFMA. 768 threads, 12 waves = 12 ct tiles, 1 ct/wave;
// setprio around the MFMA cluster.
// ---------------------------------------------------------------------------
__global__ __launch_bounds__(768) void proj_kernel(
    const float* __restrict__ x, const float* __restrict__ lin_b,
    const short* __restrict__ w3hi, const short* __restrict__ w3lo,
    float2* __restrict__ vx, float* __restrict__ xdW)
{
    const int n0 = blockIdx.x * 32;
    const int tid = threadIdx.x;
    const int ct = tid >> 6;              // wave = ct tile, 0..11
    const int lane = tid & 63;
    const int hf = lane >> 5;
    const int ln = lane & 31;

    __shared__ __align__(16) short xhi[32][XPITCH];
    __shared__ __align__(16) short xlo[32][XPITCH];

    for (int idx = tid; idx < 32 * F_INPUT; idx += 768) {
        int n = idx / F_INPUT, k = idx - n * F_INPUT;
        short hi, lo; split_bf(x[n0 * F_INPUT + idx], hi, lo);
        xhi[n][k] = hi; xlo[n][k] = lo;
    }
    if (tid < 32 * 5) {
        int n = tid / 5, k = F_INPUT + tid % 5;
        xhi[n][k] = 0; xlo[n][k] = 0;
    }
    __syncthreads();

    f32x16 acc;
    #pragma unroll
    for (int r = 0; r < 16; r++) acc[r] = 0.f;

    __builtin_amdgcn_s_setprio(1);
    #pragma unroll
    for (int s = 0; s < 4; s++) {
        bf16x8 ah = *(const bf16x8*)&xhi[ln][s * 16 + hf * 8];
        bf16x8 al = *(const bf16x8*)&xlo[ln][s * 16 + hf * 8];
        const int boff = (((ct * 4 + s) * 2 + hf) * 32 + ln) * 8;
        bf16x8 bh = *(const bf16x8*)&w3hi[boff];
        bf16x8 bl = *(const bf16x8*)&w3lo[boff];
        acc = __builtin_amdgcn_mfma_f32_32x32x16_bf16(ah, bl, acc, 0, 0, 0);
        acc = __builtin_amdgcn_mfma_f32_32x32x16_bf16(al, bh, acc, 0, 0, 0);
        acc = __builtin_amdgcn_mfma_f32_32x32x16_bf16(ah, bh, acc, 0, 0, 0);
    }
    __builtin_amdgcn_s_setprio(0);

    const int tpl = ct >> 2;              // output plane 0..2
    const int c = (ct & 3) * 32 + ln;
    if (tpl == 0) {
        const float lb = lin_b[c];
        #pragma unroll
        for (int r = 0; r < 16; r++) {
            int node = n0 + (r & 3) + 8 * (r >> 2) + 4 * hf;
            ((float*)&vx[node * H + c])[1] = acc[r] + lb;   // vx.y = v
        }
    } else if (tpl == 1) {
        #pragma unroll
        for (int r = 0; r < 16; r++) {
            int node = n0 + (r & 3) + 8 * (r >> 2) + 4 * hf;
            ((float*)&vx[node * H + c])[0] = acc[r];        // vx.x = a_src
        }
    } else {
        #pragma unroll
        for (int r = 0; r < 16; r++) {
            int node = n0 + (r & 3) + 8 * (r >> 2) + 4 * hf;
            xdW[node * H + c] = acc[r];
        }
    }
}

// ---------------------------------------------------------------------------
// Kernel B: edge stage. R16 4-node structure; R17 attnn B-lo drop;
// R18: delta A-lo (rel-lo) dropped too -- rel staged bf16-hi only, delta
// runs 2 MFMA/node (A-hi x B-lo + A-hi x B-hi, posnn B keeps hi+lo).
// rell plane deleted: LDS 43.4 -> 39.4 KB -> 4 blocks/CU; (256,4).
// Revert trigger: absmax > 0.1.
// ---------------------------------------------------------------------------
__global__ __launch_bounds__(256, 4) void edge_kernel(
    const float* __restrict__ pos, const float* __restrict__ normal,
    const int* __restrict__ src,
    const float2* __restrict__ vx, const float* __restrict__ xdW,
    const float* __restrict__ posnn_b, const float* __restrict__ posnn_g,
    const float* __restrict__ posnn_bb,
    const float* __restrict__ attnn_b,
    const float* __restrict__ attnn_g, const float* __restrict__ attnn_bb,
    const short* __restrict__ pwhi, const short* __restrict__ pwlo,
    const short* __restrict__ awhi, const short* __restrict__ awlo,
    unsigned* __restrict__ h2)
{
    // bijective chunked swizzle: 2048 blocks, 8 XCDs, 256 blocks/chunk
    const int bid = blockIdx.x;
    const int swz = (bid & 7) * 256 + (bid >> 3);
    const int i0 = swz * 4;
    const int tid = threadIdx.x;
    const int wave = tid >> 6;
    const int lane = tid & 63;
    const int hf = lane >> 5;
    const int ln = lane & 31;

    __shared__ int srcs[4][K];
    __shared__ __align__(16) short relh[128][16];
    __shared__ __align__(16) short dhi[128][DPITCH];

    if (tid < 128) {
        int n = tid >> 5, jj = tid & 31;
        int i = i0 + n;
        int s = src[i * K + jj];
        srcs[n][jj] = s;
        #pragma unroll
        for (int k = 0; k < 3; k++) {
            relh[tid][k]     = bfhi(pos[i * 3 + k] - pos[s * 3 + k]);
            relh[tid][k + 3] = bfhi(normal[i * 3 + k] - normal[s * 3 + k]);
        }
        #pragma unroll
        for (int k = 6; k < 16; k++) relh[tid][k] = 0;
    }

    // per-channel constants (c = cc for this lane)
    const int cc = wave * 32 + ln;
    const float ps  = posnn_g[cc] * rsqrtf(1.f + EPS_BN);
    const float pbn = fmaf(posnn_b[cc], ps, posnn_bb[cc]);
    const float as_ = attnn_g[cc] * rsqrtf(1.f + EPS_BN);
    const float abb = attnn_bb[cc];
    const float ab  = attnn_b[cc];

    // posnn B-frag (K16=1, ct=wave)
    const bf16x8 pbh = *(const bf16x8*)&pwhi[((wave * 2 + hf) * 32 + ln) * 8];
    const bf16x8 pbl = *(const bf16x8*)&pwlo[((wave * 2 + hf) * 32 + ln) * 8];

    // hoist the per-node alpha bases (hides L2 latency under delta phase)
    float base[4];
    #pragma unroll
    for (int n = 0; n < 4; n++) base[n] = xdW[(i0 + n) * H + cc] + ab;

    __syncthreads();

    // ---- delta via MFMA for all 4 nodes; A = rel bf16-hi, B = posnn hi+lo
    #pragma unroll
    for (int n = 0; n < 4; n++) {
        bf16x8 ah = *(const bf16x8*)&relh[32 * n + ln][hf * 8];
        f32x16 da;
        #pragma unroll
        for (int r = 0; r < 16; r++) da[r] = 0.f;
        da = __builtin_amdgcn_mfma_f32_32x32x16_bf16(ah, pbl, da, 0, 0, 0);
        da = __builtin_amdgcn_mfma_f32_32x32x16_bf16(ah, pbh, da, 0, 0, 0);
        #pragma unroll
        for (int r = 0; r < 16; r++) {
            int j = (r & 3) + 8 * (r >> 2) + 4 * hf;
            float d = fmaxf(fmaf(da[r], ps, pbn), 0.f);
            dhi[32 * n + j][cc] = (short)(__float_as_uint(d) >> 16);
        }
    }
    __syncthreads();

    // ---- attnn MFMA: s-loop outer; ONE bh-frag load feeds 4 nodes,
    //      1 MFMA per s per node (B-lo dropped).
    const short* whb = awhi + wave * 8 * 2 * 32 * 8;

    f32x16 acc[4];
    #pragma unroll
    for (int n = 0; n < 4; n++)
        #pragma unroll
        for (int r = 0; r < 16; r++) acc[n][r] = base[n];

    __builtin_amdgcn_s_setprio(1);
    #pragma unroll
    for (int s = 0; s < 8; s++) {
        const int boff = ((s * 2 + hf) * 32 + ln) * 8;
        bf16x8 bh = *(const bf16x8*)&whb[boff];
        #pragma unroll
        for (int n = 0; n < 4; n++) {
            bf16x8 ah = *(const bf16x8*)&dhi[32 * n + ln][s * 16 + hf * 8];
            acc[n] = __builtin_amdgcn_mfma_f32_32x32x16_bf16(ah, bh, acc[n], 0, 0, 0);
        }
    }
    __builtin_amdgcn_s_setprio(0);

    // ---- softmax epilogue per node (gathers issued here; 16 in flight)
    #pragma unroll
    for (int n = 0; n < 4; n++) {
        const int i = i0 + n;
        float2 gvn[16];
        #pragma unroll
        for (int r = 0; r < 16; r++) {
            int j = (r & 3) + 8 * (r >> 2) + 4 * hf;
            gvn[r] = vx[srcs[n][j] * H + cc];
        }
        float a[16], vv[16];
        #pragma unroll
        for (int r = 0; r < 16; r++) {
            int j = (r & 3) + 8 * (r >> 2) + 4 * hf;
            unsigned dh = (unsigned short)dhi[32 * n + j][cc];
            float av = fmaxf(fmaf(acc[n][r] - gvn[r].x, as_, abb), 0.f);
            a[r] = av;
            vv[r] = gvn[r].y + __uint_as_float(dh << 16);
        }
        // depth-4 max tree (all a[] >= 0 from relu)
        float m01 = fmaxf(a[0], a[1]),  m23 = fmaxf(a[2], a[3]);
        float m45 = fmaxf(a[4], a[5]),  m67 = fmaxf(a[6], a[7]);
        float m89 = fmaxf(a[8], a[9]),  mab = fmaxf(a[10], a[11]);
        float mcd = fmaxf(a[12], a[13]), mef = fmaxf(a[14], a[15]);
        float m0123 = fmaxf(m01, m23), m4567 = fmaxf(m45, m67);
        float m89ab = fmaxf(m89, mab), mcdef = fmaxf(mcd, mef);
        float m = fmaxf(fmaxf(m0123, m4567), fmaxf(m89ab, mcdef));
        m = fmaxf(m, __shfl_xor(m, 32, 64));

        float dac0 = 0.f, dac1 = 0.f, dac2 = 0.f, dac3 = 0.f;
        float hac0 = 0.f, hac1 = 0.f, hac2 = 0.f, hac3 = 0.f;
        #pragma unroll
        for (int r = 0; r < 16; r += 4) {
            float e0 = __expf(a[r + 0] - m);
            float e1 = __expf(a[r + 1] - m);
            float e2 = __expf(a[r + 2] - m);
            float e3 = __expf(a[r + 3] - m);
            dac0 += e0; dac1 += e1; dac2 += e2; dac3 += e3;
            hac0 = fmaf(e0, vv[r + 0], hac0);
            hac1 = fmaf(e1, vv[r + 1], hac1);
            hac2 = fmaf(e2, vv[r + 2], hac2);
            hac3 = fmaf(e3, vv[r + 3], hac3);
        }
        float den = (dac0 + dac1) + (dac2 + dac3);
        float hsum = (hac0 + hac1) + (hac2 + hac3);
        den += __shfl_xor(den, 32, 64);
        hsum += __shfl_xor(hsum, 32, 64);
        hsum *= 1.f / (den + 1e-16f);
        if (hf == 0) {
            unsigned u = __float_as_uint(hsum);
            unsigned hib = u & 0xffff0000u;
            unsigned lo = __float_as_uint(hsum - __uint_as_float(hib)) >> 16;
            h2[i * H + cc] = (lo << 16) | (u >> 16);
        }
    }
}

// ---------------------------------------------------------------------------
// Kernel C (fused): neck MFMA + bn_relu + residue max-pool + head.
// 1024 threads, 16 waves, 1 ct/wave, mlp1 16-way k-split; setprio on MFMA.
// ---------------------------------------------------------------------------
__global__ __launch_bounds__(1024) void neck_head_kernel(
    const unsigned* __restrict__ h2,
    const short* __restrict__ nwhi, const short* __restrict__ nwlo,
    const float* __restrict__ neck_b, const float* __restrict__ neck_g,
    const float* __restrict__ neck_bb,
    const float* __restrict__ mask_t,
    const float* __restrict__ mlp1_w, const float* __restrict__ mlp1_b,
    const float* __restrict__ mlp1_g, const float* __restrict__ mlp1_bb,
    const float* __restrict__ mlp2_w, const float* __restrict__ mlp2_b,
    float* __restrict__ out)
{
    const int blk = blockIdx.x;
    const int n0 = blk * 32;
    const int tid = threadIdx.x;
    const int wave = tid >> 6;            // 0..15
    const int lane = tid & 63;
    const int hf = lane >> 5;
    const int ln = lane & 31;

    __shared__ __align__(16) short a_hi[32][DPITCH];
    __shared__ __align__(16) short a_lo[32][DPITCH];
    __shared__ float gfeat_l[4][NECK];
    __shared__ float red_l[16][4][256];

    for (int d = tid; d < 32 * H; d += 1024) {
        unsigned u = h2[(n0 + (d >> 7)) * H + (d & 127)];
        a_hi[d >> 7][d & 127] = (short)(u & 0xffffu);
        a_lo[d >> 7][d & 127] = (short)(u >> 16);
    }
    __syncthreads();

    f32x16 acc;
    #pragma unroll
    for (int r = 0; r < 16; r++) acc[r] = 0.f;

    const int ct = wave;                  // 1 ct tile per wave
    __builtin_amdgcn_s_setprio(1);
    #pragma unroll
    for (int s = 0; s < 8; s++) {
        bf16x8 ah = *(const bf16x8*)&a_hi[ln][s * 16 + hf * 8];
        bf16x8 al = *(const bf16x8*)&a_lo[ln][s * 16 + hf * 8];
        const int boff = (((ct * 8 + s) * 2 + hf) * 32 + ln) * 8;
        bf16x8 bh = *(const bf16x8*)&nwhi[boff];
        bf16x8 bl = *(const bf16x8*)&nwlo[boff];
        acc = __builtin_amdgcn_mfma_f32_32x32x16_bf16(ah, bl, acc, 0, 0, 0);
        acc = __builtin_amdgcn_mfma_f32_32x32x16_bf16(al, bh, acc, 0, 0, 0);
        acc = __builtin_amdgcn_mfma_f32_32x32x16_bf16(ah, bh, acc, 0, 0, 0);
    }
    __builtin_amdgcn_s_setprio(0);

    {
        const int c = ct * 32 + ln;
        const float s  = neck_g[c] * rsqrtf(1.f + EPS_BN);
        const float bnb = fmaf(neck_b[c], s, neck_bb[c]);
        #pragma unroll
        for (int g = 0; g < 4; g++) {
            float m = 0.f;
            #pragma unroll
            for (int q = 0; q < 4; q++)
                m = fmaxf(m, fmaf(acc[4 * g + q], s, bnb));
            m = fmaxf(m, __shfl_xor(m, 32, 64));
            if (hf == 0) gfeat_l[g][c] = m;
        }
    }
    __syncthreads();

    const int c4 = lane;
    float ph[4][4];
    #pragma unroll
    for (int g = 0; g < 4; g++)
        #pragma unroll
        for (int mm = 0; mm < 4; mm++) ph[g][mm] = 0.f;

    const int k0 = wave * 32;             // 32 k per wave
    for (int k = 0; k < 32; k += 4) {
        float4 gv[4];
        #pragma unroll
        for (int g = 0; g < 4; g++) gv[g] = *(const float4*)&gfeat_l[g][k0 + k];
        #pragma unroll
        for (int kk = 0; kk < 4; kk++) {
            float w0 = mlp1_w[(k0 + k + kk) * 256 + c4];
            float w1 = mlp1_w[(k0 + k + kk) * 256 + c4 + 64];
            float w2 = mlp1_w[(k0 + k + kk) * 256 + c4 + 128];
            float w3 = mlp1_w[(k0 + k + kk) * 256 + c4 + 192];
            #pragma unroll
            for (int g = 0; g < 4; g++) {
                float gvk = (&gv[g].x)[kk];
                ph[g][0] = fmaf(gvk, w0, ph[g][0]);
                ph[g][1] = fmaf(gvk, w1, ph[g][1]);
                ph[g][2] = fmaf(gvk, w2, ph[g][2]);
                ph[g][3] = fmaf(gvk, w3, ph[g][3]);
            }
        }
    }
    #pragma unroll
    for (int g = 0; g < 4; g++)
        #pragma unroll
        for (int mm = 0; mm < 4; mm++)
            red_l[wave][g][c4 + 64 * mm] = ph[g][mm];
    __syncthreads();

    if (wave < 4) {
        const int g = wave;
        float part = 0.f;
        #pragma unroll
        for (int mm = 0; mm < 4; mm++) {
            const int c = c4 + 64 * mm;
            float sum = mlp1_b[c];
            #pragma unroll
            for (int w = 0; w < 16; w++) sum += red_l[w][g][c];
            float s = mlp1_g[c] * rsqrtf(1.f + EPS_BN);
            float val = fmaxf(fmaf(sum, s, mlp1_bb[c]), 0.f);
            part = fmaf(val, mlp2_w[c], part);
        }
        #pragma unroll
        for (int off = 32; off > 0; off >>= 1) part += __shfl_xor(part, off, 64);
        if (lane == 0) {
            const int gg = blk * 4 + g;
            float mm = mask_t[gg * GPER];
            #pragma unroll
            for (int n = 1; n < GPER; n++) mm = fmaxf(mm, mask_t[gg * GPER + n]);
            out[gg] = (mm == 1.0f) ? (part + mlp2_b[0]) : 0.f;
        }
    }
}

// ---------------------------------------------------------------------------
extern "C" void kernel_launch(void* const* d_in, const int* in_sizes, int n_in,
                              void* d_out, int out_size, void* d_ws, size_t ws_size,
                              hipStream_t stream)
{
    const float* x        = (const float*)d_in[0];
    const float* pos      = (const float*)d_in[1];
    const float* normal   = (const float*)d_in[2];
    const float* mask_t   = (const float*)d_in[3];
    const int*   src      = (const int*)d_in[5];
    const float* lin_w    = (const float*)d_in[7];
    const float* lin_b    = (const float*)d_in[8];
    const float* src_w    = (const float*)d_in[9];
    const float* dst_w    = (const float*)d_in[10];
    const float* posnn_w  = (const float*)d_in[11];
    const float* posnn_b  = (const float*)d_in[12];
    const float* posnn_g  = (const float*)d_in[13];
    const float* posnn_bb = (const float*)d_in[14];
    const float* attnn_w  = (const float*)d_in[15];
    const float* attnn_b  = (const float*)d_in[16];
    const float* attnn_g  = (const float*)d_in[17];
    const float* attnn_bb = (const float*)d_in[18];
    const float* neck_w   = (const float*)d_in[19];
    const float* neck_b   = (const float*)d_in[20];
    const float* neck_g   = (const float*)d_in[21];
    const float* neck_bb  = (const float*)d_in[22];
    const float* mlp1_w   = (const float*)d_in[23];
    const float* mlp1_b   = (const float*)d_in[24];
    const float* mlp1_g   = (const float*)d_in[25];
    const float* mlp1_bb  = (const float*)d_in[26];
    const float* mlp2_w   = (const float*)d_in[27];
    const float* mlp2_b   = (const float*)d_in[28];

    float* ws = (float*)d_ws;
    float2*   vx   = (float2*)ws;                              // N*H float2
    float*    xdW  = (float*)(vx + (size_t)N_NODES * H);       // N*H
    unsigned* h2   = (unsigned*)(xdW + (size_t)N_NODES * H);   // N*H
    short*    w3hi = (short*)(h2 + (size_t)N_NODES * H);       // 24576
    short*    w3lo = w3hi + 24576;
    short*    pwhi = w3lo + 24576;                             // 2048
    short*    pwlo = pwhi + 2048;
    short*    awhi = pwlo + 2048;                              // 16384
    short*    awlo = awhi + H * H;
    short*    nwhi = awlo + H * H;                             // 65536
    short*    nwlo = nwhi + H * NECK;

    prep_kernel<<<F_INPUT + 2 + 64 + 256, 256, 0, stream>>>(
        lin_w, src_w, dst_w, posnn_w, attnn_w, neck_w,
        w3hi, w3lo, pwhi, pwlo, awhi, awlo, nwhi, nwlo);
    proj_kernel<<<N_NODES / 32, 768, 0, stream>>>(x, lin_b, w3hi, w3lo, vx, xdW);
    edge_kernel<<<N_NODES / 4, 256, 0, stream>>>(pos, normal, src, vx, xdW,
                                                 posnn_b, posnn_g, posnn_bb,
                                                 attnn_b, attnn_g, attnn_bb,
                                                 pwhi, pwlo, awhi, awlo, h2);
    neck_head_kernel<<<N_NODES / 32, 1024, 0, stream>>>(
        h2, nwhi, nwlo, neck_b, neck_g, neck_bb, mask_t,
        mlp1_w, mlp1_b, mlp1_g, mlp1_bb, mlp2_w, mlp2_b, (float*)d_out);
}